// Round 10
// baseline (1539.028 us; speedup 1.0000x reference)
//
#include <hip/hip_runtime.h>
#include <math.h>

#define N_NODES 100000
#define N_EDGES 1600000
#define NB     391   // buckets of 256 nodes
#define CHUNK  4096  // edges per chunk block
#define NBLK_A 391   // ceil(E/CHUNK)
#define SCAP   5632  // max edges per bucket (mean 4092, +24 sigma)
#define ACC_LD 65    // accumulator row stride (floats) — spreads LDS-atomic banks

typedef unsigned short ushort_t;

__device__ inline unsigned short f2bf(float f) {
    unsigned u = __float_as_uint(f);
    unsigned r = (u + 0x7FFFu + ((u >> 16) & 1u)) >> 16;
    return (unsigned short)r;
}
// tanh(x) = 1 - 2/(exp(2x)+1); saturates correctly at +-1, err ~1e-6
__device__ inline float fast_tanh(float x) {
    float e = __expf(2.0f * x);
    return fmaf(-2.0f, __builtin_amdgcn_rcpf(e + 1.0f), 1.0f);
}
// acc += a.x*w0 + a.y*w1 + a.z*w2 + a.w*w3 (component-wise over 4 cols)
__device__ inline void fma4(float4& acc, const float4 a,
                            const float4 w0, const float4 w1,
                            const float4 w2, const float4 w3) {
    acc.x = fmaf(a.x, w0.x, fmaf(a.y, w1.x, fmaf(a.z, w2.x, fmaf(a.w, w3.x, acc.x))));
    acc.y = fmaf(a.x, w0.y, fmaf(a.y, w1.y, fmaf(a.z, w2.y, fmaf(a.w, w3.y, acc.y))));
    acc.z = fmaf(a.x, w0.z, fmaf(a.y, w1.z, fmaf(a.z, w2.z, fmaf(a.w, w3.z, acc.z))));
    acc.w = fmaf(a.x, w0.w, fmaf(a.y, w1.w, fmaf(a.z, w2.w, fmaf(a.w, w3.w, acc.w))));
}
// scatter 4 bf16 (uint2) into LDS accumulator row of node (e&255)
__device__ inline void scat(float* acc, unsigned e, int l, uint2 v) {
    float* p = acc + (e & 255u) * ACC_LD + l * 4;
    atomicAdd(p + 0, __uint_as_float(v.x << 16));
    atomicAdd(p + 1, __uint_as_float(v.x & 0xFFFF0000u));
    atomicAdd(p + 2, __uint_as_float(v.y << 16));
    atomicAdd(p + 3, __uint_as_float(v.y & 0xFFFF0000u));
}

// ---------------- CSR-free edge binning: deterministic 3-level multisplit ----------------

__global__ __launch_bounds__(256) void k_count(const int* __restrict__ dst,
                                               unsigned* __restrict__ cnt) {
    __shared__ unsigned h[NB];
    const int tid = threadIdx.x;
    const long e0 = (long)blockIdx.x * CHUNK;
    for (int i = tid; i < NB; i += 256) h[i] = 0u;
    __syncthreads();
    for (int i = tid; i < CHUNK; i += 256) {
        long e = e0 + i;
        if (e < N_EDGES) atomicAdd(&h[((unsigned)dst[e]) >> 8], 1u);
    }
    __syncthreads();
    for (int b = tid; b < NB; b += 256) cnt[b * NBLK_A + blockIdx.x] = h[b];
}

__global__ __launch_bounds__(512) void k_bucket_scan(unsigned* __restrict__ cnt,
                                                     unsigned* __restrict__ btot) {
    __shared__ unsigned s[512];
    const int tid = threadIdx.x;
    const int b = blockIdx.x;
    unsigned v = (tid < NBLK_A) ? cnt[b * NBLK_A + tid] : 0u;
    s[tid] = v;
    __syncthreads();
    for (int o = 1; o < 512; o <<= 1) {
        unsigned t = (tid >= o) ? s[tid - o] : 0u;
        __syncthreads();
        s[tid] += t;
        __syncthreads();
    }
    if (tid < NBLK_A) cnt[b * NBLK_A + tid] = s[tid] - v;   // exclusive within bucket
    if (tid == NBLK_A - 1) btot[b] = s[tid];
}

__global__ __launch_bounds__(512) void k_scan_bkt(const unsigned* __restrict__ btot,
                                                  unsigned* __restrict__ bktbase) {
    __shared__ unsigned s[512];
    const int tid = threadIdx.x;
    unsigned v = (tid < NB) ? btot[tid] : 0u;
    s[tid] = v;
    __syncthreads();
    for (int o = 1; o < 512; o <<= 1) {
        unsigned t = (tid >= o) ? s[tid - o] : 0u;
        __syncthreads();
        s[tid] += t;
        __syncthreads();
    }
    if (tid < NB) bktbase[tid] = s[tid] - v;
    if (tid == NB - 1) bktbase[NB] = s[tid];   // == E
}

// phase A: LDS multisplit into 391 dst-buckets; binned[pos] = (src<<8)|(dst&255)
__global__ __launch_bounds__(256) void k_bin(const int* __restrict__ src,
                                             const int* __restrict__ dst,
                                             const unsigned* __restrict__ cnt,
                                             const unsigned* __restrict__ bktbase,
                                             unsigned* __restrict__ binned) {
    __shared__ unsigned cntA[NB];
    __shared__ unsigned excl[NB];
    __shared__ unsigned gbase[NB];
    __shared__ unsigned scanbuf[512];
    __shared__ unsigned data[CHUNK];
    const int tid = threadIdx.x;
    const long e0 = (long)blockIdx.x * CHUNK;

    for (int i = tid; i < NB; i += 256) cntA[i] = 0u;
    __syncthreads();
    for (int i = tid; i < CHUNK; i += 256) {
        long e = e0 + i;
        if (e < N_EDGES) atomicAdd(&cntA[((unsigned)dst[e]) >> 8], 1u);
    }
    __syncthreads();
    scanbuf[tid] = (tid < NB) ? cntA[tid] : 0u;
    scanbuf[tid + 256] = (tid + 256 < NB) ? cntA[tid + 256] : 0u;
    __syncthreads();
    for (int o = 1; o < 512; o <<= 1) {
        unsigned v0 = (tid >= o) ? scanbuf[tid - o] : 0u;
        unsigned v1 = (tid + 256 >= o) ? scanbuf[tid + 256 - o] : 0u;
        __syncthreads();
        scanbuf[tid] += v0;
        scanbuf[tid + 256] += v1;
        __syncthreads();
    }
    for (int b = tid; b < NB; b += 256) {
        excl[b] = scanbuf[b] - cntA[b];
        gbase[b] = bktbase[b] + cnt[b * NBLK_A + blockIdx.x];
    }
    __syncthreads();
    for (int i = tid; i < NB; i += 256) cntA[i] = 0u;
    __syncthreads();
    for (int i = tid; i < CHUNK; i += 256) {
        long e = e0 + i;
        if (e < N_EDGES) {
            unsigned d = (unsigned)dst[e];
            unsigned b = d >> 8;
            unsigned slot = excl[b] + atomicAdd(&cntA[b], 1u);
            data[slot] = (((unsigned)src[e]) << 8) | (d & 255u);
        }
    }
    __syncthreads();
    const int w = tid >> 6, lane = tid & 63;
    for (int b = w; b < NB; b += 4) {
        unsigned c = cntA[b];
        unsigned sb = excl[b], gb = gbase[b];
        for (unsigned k = lane; k < c; k += 64)
            binned[gb + k] = data[sb + k];
    }
}

// phase B: sort each bucket's edges by coarse src tile (src>>8) so all blocks
// sweep xlb in ascending src order (L2 window locality); also computes dinv.
__global__ __launch_bounds__(512) void k_sort(unsigned* __restrict__ binned,
                                              const unsigned* __restrict__ bktbase,
                                              float* __restrict__ dinv) {
    __shared__ unsigned data[SCAP];
    __shared__ unsigned cnt[NB];
    __shared__ unsigned excl[NB];
    __shared__ unsigned scanbuf[512];
    __shared__ unsigned deg[256];
    const int b = blockIdx.x, tid = threadIdx.x;
    const unsigned beg = bktbase[b], end = bktbase[b + 1];
    const int n = (int)(end - beg);
    for (int i = tid; i < NB; i += 512) cnt[i] = 0u;
    if (tid < 256) deg[tid] = 0u;
    __syncthreads();
    for (int i = tid; i < n; i += 512) {
        unsigned e = binned[beg + i];
        data[i] = e;
        atomicAdd(&cnt[e >> 16], 1u);        // coarse src tile = src>>8
        atomicAdd(&deg[e & 255u], 1u);
    }
    __syncthreads();
    scanbuf[tid] = (tid < NB) ? cnt[tid] : 0u;
    __syncthreads();
    for (int o = 1; o < 512; o <<= 1) {
        unsigned t = (tid >= o) ? scanbuf[tid - o] : 0u;
        __syncthreads();
        scanbuf[tid] += t;
        __syncthreads();
    }
    if (tid < NB) excl[tid] = scanbuf[tid] - cnt[tid];
    {
        const int node = b * 256 + tid;
        if (tid < 256 && node < N_NODES)
            dinv[node] = rsqrtf((float)(deg[tid] + 1u));
    }
    for (int i = tid; i < NB; i += 512) cnt[i] = 0u;
    __syncthreads();
    for (int i = tid; i < n; i += 512) {
        unsigned e = data[i];
        unsigned t = e >> 16;
        unsigned pos = excl[t] + atomicAdd(&cnt[t], 1u);
        binned[beg + pos] = e;
    }
}

// ---------------- dense layers ----------------

// xlb[N x 64] (bf16) = (A[N x K] @ W[K x 64]) * dinv[row]
// 64 rows x 64 cols per 256-thread block; 4x4 register tile per thread.
template<int K>
__global__ __launch_bounds__(256) void k_gemm_bf(const float* __restrict__ A,
                                                 const float* __restrict__ W,
                                                 const float* __restrict__ dinv,
                                                 ushort_t* __restrict__ C) {
    constexpr int OUT = 64;
    constexpr int BR = 64;
    constexpr int LDA = K + 4;
    __shared__ float Wld[K * OUT];
    __shared__ float Ald[BR * LDA];
    const int tid = threadIdx.x;
    const int row0 = blockIdx.x * BR;
    const int nrows = (N_NODES - row0 < BR) ? (N_NODES - row0) : BR;

    {
        const float4* W4 = reinterpret_cast<const float4*>(W);
        float4* Wl4 = reinterpret_cast<float4*>(Wld);
        for (int i = tid; i < K * OUT / 4; i += 256) Wl4[i] = W4[i];
        const float4* A4 = reinterpret_cast<const float4*>(A + (size_t)row0 * K);
        const int nv = nrows * (K / 4);
        for (int i = tid; i < nv; i += 256) {
            int r = i / (K / 4), q = i % (K / 4);
            *reinterpret_cast<float4*>(&Ald[r * LDA + q * 4]) = A4[i];
        }
    }
    __syncthreads();

    const int tr = tid >> 4;
    const int tc = tid & 15;
    const int r0 = tr * 4;
    float4 acc0 = {0,0,0,0}, acc1 = {0,0,0,0}, acc2 = {0,0,0,0}, acc3 = {0,0,0,0};
#pragma unroll 2
    for (int k4 = 0; k4 < K; k4 += 4) {
        const float4 a0 = *reinterpret_cast<const float4*>(&Ald[(r0 + 0) * LDA + k4]);
        const float4 a1 = *reinterpret_cast<const float4*>(&Ald[(r0 + 1) * LDA + k4]);
        const float4 a2 = *reinterpret_cast<const float4*>(&Ald[(r0 + 2) * LDA + k4]);
        const float4 a3 = *reinterpret_cast<const float4*>(&Ald[(r0 + 3) * LDA + k4]);
        const float4 w0 = *reinterpret_cast<const float4*>(&Wld[(k4 + 0) * OUT + tc * 4]);
        const float4 w1 = *reinterpret_cast<const float4*>(&Wld[(k4 + 1) * OUT + tc * 4]);
        const float4 w2 = *reinterpret_cast<const float4*>(&Wld[(k4 + 2) * OUT + tc * 4]);
        const float4 w3 = *reinterpret_cast<const float4*>(&Wld[(k4 + 3) * OUT + tc * 4]);
        fma4(acc0, a0, w0, w1, w2, w3);
        fma4(acc1, a1, w0, w1, w2, w3);
        fma4(acc2, a2, w0, w1, w2, w3);
        fma4(acc3, a3, w0, w1, w2, w3);
    }
    float4 accs[4] = {acc0, acc1, acc2, acc3};
#pragma unroll
    for (int i = 0; i < 4; ++i) {
        const int r = r0 + i;
        if (r < nrows) {
            const float di = dinv[row0 + r];
            ushort4 o;
            o.x = f2bf(accs[i].x * di);
            o.y = f2bf(accs[i].y * di);
            o.z = f2bf(accs[i].z * di);
            o.w = f2bf(accs[i].w * di);
            *reinterpret_cast<ushort4*>(&C[(size_t)(row0 + r) * 64 + tc * 4]) = o;
        }
    }
}

// bucket-major aggregation: one block per dst-bucket (256 nodes), LDS fp32
// accumulator; edges pre-sorted by src so co-resident blocks sweep xlb together.
__global__ __launch_bounds__(256) void k_agg_b(const ushort_t* __restrict__ xlb,
                                               const float* __restrict__ dinv,
                                               const unsigned* __restrict__ bktbase,
                                               const unsigned* __restrict__ binned,
                                               const float* __restrict__ bias,
                                               float* __restrict__ h) {
    __shared__ float accum[256 * ACC_LD];   // 66,560 B -> 2 blocks/CU
    const int b = blockIdx.x;
    const int tid = threadIdx.x;
    const int n0 = b * 256;
    const unsigned beg = bktbase[b], end = bktbase[b + 1];
    for (int i = tid; i < 256 * ACC_LD; i += 256) accum[i] = 0.f;
    __syncthreads();

    const int lane = tid & 63;
    const int wid = tid >> 6;
    const int g = lane >> 4;     // edge slot within wave
    const int l = lane & 15;     // feature quad
    const uint2* xb2 = reinterpret_cast<const uint2*>(xlb);

    unsigned i = beg + wid * 4 + g;
    for (; i + 48 < end; i += 64) {   // 4 gathers in flight per wave
        const unsigned e0 = binned[i];
        const unsigned e1 = binned[i + 16];
        const unsigned e2 = binned[i + 32];
        const unsigned e3 = binned[i + 48];
        const uint2 v0 = xb2[(size_t)(e0 >> 8) * 16 + l];
        const uint2 v1 = xb2[(size_t)(e1 >> 8) * 16 + l];
        const uint2 v2 = xb2[(size_t)(e2 >> 8) * 16 + l];
        const uint2 v3 = xb2[(size_t)(e3 >> 8) * 16 + l];
        scat(accum, e0, l, v0);
        scat(accum, e1, l, v1);
        scat(accum, e2, l, v2);
        scat(accum, e3, l, v3);
    }
    for (; i < end; i += 16) {
        const unsigned e = binned[i];
        const uint2 v = xb2[(size_t)(e >> 8) * 16 + l];
        scat(accum, e, l, v);
    }
    __syncthreads();

    // epilogue: wave wid handles nodes n = wid + 4k; lane = feature
    const int f = lane;
    const float bf = bias[f];
    for (int n = wid; n < 256; n += 4) {
        const int node = n0 + n;
        if (node < N_NODES) {
            const float self = __uint_as_float(((unsigned)xlb[(size_t)node * 64 + f]) << 16);
            const float v = accum[n * ACC_LD + f] + self;
            h[(size_t)node * 64 + f] = fast_tanh(fmaf(v, dinv[node], bf));
        }
    }
}

// fused FC stack, register-tiled fp32 with controlled unrolling + fast_tanh.
__global__ __launch_bounds__(256, 4) void k_fc(const float* __restrict__ h2,
                                               const float* __restrict__ fW0, const float* __restrict__ fb0,
                                               const float* __restrict__ fW1, const float* __restrict__ fb1,
                                               const float* __restrict__ fW2, const float* __restrict__ fb2,
                                               float* __restrict__ out) {
    constexpr int BR = 32;
    constexpr int LDH = 68;
    __shared__ float W0[64 * 64];
    __shared__ float W1[64 * 32];
    __shared__ float Hin[BR * LDH];
    __shared__ float Ht[BR * LDH];
    __shared__ float Hs[BR * 33];
    __shared__ float W2s[33];
    const int tid = threadIdx.x;
    {
        const float4* w04 = reinterpret_cast<const float4*>(fW0);
        float4* W04 = reinterpret_cast<float4*>(W0);
        for (int i = tid; i < 64 * 16; i += 256) W04[i] = w04[i];
        const float4* w14 = reinterpret_cast<const float4*>(fW1);
        float4* W14 = reinterpret_cast<float4*>(W1);
        for (int i = tid; i < 64 * 8; i += 256) W14[i] = w14[i];
        if (tid < 32) W2s[tid] = fW2[tid];
        if (tid == 32) W2s[32] = fb2[0];
    }
    const long row0 = (long)blockIdx.x * BR;
    {
        const float4* H4 = reinterpret_cast<const float4*>(h2 + row0 * 64);
        for (int i = tid; i < BR * 16; i += 256) {
            int r = i >> 4, q = i & 15;
            *reinterpret_cast<float4*>(&Hin[r * LDH + q * 4]) = H4[i];
        }
    }
    __syncthreads();

    {
        const int rp = tid >> 4;
        const int cq = tid & 15;
        const int r0 = rp * 2, r1 = r0 + 1;
        const float4 bias = reinterpret_cast<const float4*>(fb0)[cq];
        float4 acc0 = bias, acc1 = bias;
#pragma unroll 2
        for (int k4 = 0; k4 < 64; k4 += 4) {
            const float4 a0 = *reinterpret_cast<const float4*>(&Hin[r0 * LDH + k4]);
            const float4 a1 = *reinterpret_cast<const float4*>(&Hin[r1 * LDH + k4]);
            const float4 w0 = *reinterpret_cast<const float4*>(&W0[(k4 + 0) * 64 + cq * 4]);
            const float4 w1 = *reinterpret_cast<const float4*>(&W0[(k4 + 1) * 64 + cq * 4]);
            const float4 w2 = *reinterpret_cast<const float4*>(&W0[(k4 + 2) * 64 + cq * 4]);
            const float4 w3 = *reinterpret_cast<const float4*>(&W0[(k4 + 3) * 64 + cq * 4]);
            fma4(acc0, a0, w0, w1, w2, w3);
            fma4(acc1, a1, w0, w1, w2, w3);
        }
        float4 t0, t1;
        t0.x = fast_tanh(acc0.x); t0.y = fast_tanh(acc0.y);
        t0.z = fast_tanh(acc0.z); t0.w = fast_tanh(acc0.w);
        t1.x = fast_tanh(acc1.x); t1.y = fast_tanh(acc1.y);
        t1.z = fast_tanh(acc1.z); t1.w = fast_tanh(acc1.w);
        *reinterpret_cast<float4*>(&Ht[r0 * LDH + cq * 4]) = t0;
        *reinterpret_cast<float4*>(&Ht[r1 * LDH + cq * 4]) = t1;
    }
    __syncthreads();

    {
        const int r = tid >> 3;
        const int cq = tid & 7;
        const float4 bias = reinterpret_cast<const float4*>(fb1)[cq];
        float4 acc0 = bias;
#pragma unroll 2
        for (int k4 = 0; k4 < 64; k4 += 4) {
            const float4 a0 = *reinterpret_cast<const float4*>(&Ht[r * LDH + k4]);
            const float4 w0 = *reinterpret_cast<const float4*>(&W1[(k4 + 0) * 32 + cq * 4]);
            const float4 w1 = *reinterpret_cast<const float4*>(&W1[(k4 + 1) * 32 + cq * 4]);
            const float4 w2 = *reinterpret_cast<const float4*>(&W1[(k4 + 2) * 32 + cq * 4]);
            const float4 w3 = *reinterpret_cast<const float4*>(&W1[(k4 + 3) * 32 + cq * 4]);
            fma4(acc0, a0, w0, w1, w2, w3);
        }
        Hs[r * 33 + cq * 4 + 0] = fast_tanh(acc0.x);
        Hs[r * 33 + cq * 4 + 1] = fast_tanh(acc0.y);
        Hs[r * 33 + cq * 4 + 2] = fast_tanh(acc0.z);
        Hs[r * 33 + cq * 4 + 3] = fast_tanh(acc0.w);
    }
    __syncthreads();

    if (tid < BR) {
        float a = W2s[32];
        for (int k = 0; k < 32; ++k) a = fmaf(Hs[tid * 33 + k], W2s[k], a);
        out[row0 + tid] = a;
    }
}

// ---------------- launch ----------------

extern "C" void kernel_launch(void* const* d_in, const int* in_sizes, int n_in,
                              void* d_out, int out_size, void* d_ws, size_t ws_size,
                              hipStream_t stream) {
    const float* x    = (const float*)d_in[0];
    const int*   eidx = (const int*)d_in[1];
    const float* cW0  = (const float*)d_in[2];
    const float* cb0  = (const float*)d_in[3];
    const float* cW1  = (const float*)d_in[4];
    const float* cb1  = (const float*)d_in[5];
    const float* fW0  = (const float*)d_in[6];
    const float* fb0  = (const float*)d_in[7];
    const float* fW1  = (const float*)d_in[8];
    const float* fb1  = (const float*)d_in[9];
    const float* fW2  = (const float*)d_in[10];
    const float* fb2  = (const float*)d_in[11];
    float* out = (float*)d_out;

    const int* src = eidx;
    const int* dst = eidx + N_EDGES;

    char* ws = (char*)d_ws;
    float*    dinv    = (float*)   (ws);                  // 400,000 B
    unsigned* cnt     = (unsigned*)(ws + 400000);         // 611,524 B
    unsigned* btot    = (unsigned*)(ws + 1011584);        // 1,564 B
    unsigned* bktbase = (unsigned*)(ws + 1013152);        // 1,568 B
    unsigned* binned  = (unsigned*)(ws + 1014720);        // 6,400,000 B
    ushort_t* xlb     = (ushort_t*)(ws + 7414720);        // 12,800,000 B
    float*    bufB    = (float*)   (ws + 20214720);       // 25,600,000 B -> ends 45,814,720

    const int gRow = N_NODES / 32;              // 3125 (k_fc)
    const int gGemm = (N_NODES + 63) / 64;      // 1563

    // edge binning + per-bucket src sort + dinv (no global fine-grained atomics)
    k_count<<<NBLK_A, 256, 0, stream>>>(dst, cnt);
    k_bucket_scan<<<NB, 512, 0, stream>>>(cnt, btot);
    k_scan_bkt<<<1, 512, 0, stream>>>(btot, bktbase);
    k_bin<<<NBLK_A, 256, 0, stream>>>(src, dst, cnt, bktbase, binned);
    k_sort<<<NB, 512, 0, stream>>>(binned, bktbase, dinv);

    // conv0
    k_gemm_bf<128><<<gGemm, 256, 0, stream>>>(x, cW0, dinv, xlb);
    k_agg_b<<<NB, 256, 0, stream>>>(xlb, dinv, bktbase, binned, cb0, bufB);
    // conv1
    k_gemm_bf<64><<<gGemm, 256, 0, stream>>>(bufB, cW1, dinv, xlb);
    k_agg_b<<<NB, 256, 0, stream>>>(xlb, dinv, bktbase, binned, cb1, bufB);
    // fc stack
    k_fc<<<gRow, 256, 0, stream>>>(bufB, fW0, fb0, fW1, fb1, fW2, fb2, out);
}

// Round 11
// 249.843 us; speedup vs baseline: 6.1600x; 6.1600x over previous
//
#include <hip/hip_runtime.h>
#include <math.h>

#define N_NODES 100000
#define N_EDGES 1600000
#define NB     391   // buckets of 256 nodes
#define CHUNK  4096  // edges per chunk block
#define NBLK_A 391   // ceil(E/CHUNK)

typedef unsigned short ushort_t;

__device__ inline unsigned short f2bf(float f) {
    unsigned u = __float_as_uint(f);
    unsigned r = (u + 0x7FFFu + ((u >> 16) & 1u)) >> 16;
    return (unsigned short)r;
}
// accumulate 2 packed bf16 (lo=feature 2k, hi=2k+1) into 2 fp32
__device__ inline void acc2(float& a0, float& a1, unsigned u) {
    a0 += __uint_as_float(u << 16);
    a1 += __uint_as_float(u & 0xFFFF0000u);
}
// tanh(x) = 1 - 2/(exp(2x)+1); saturates correctly at +-1, err ~1e-6
__device__ inline float fast_tanh(float x) {
    float e = __expf(2.0f * x);
    return fmaf(-2.0f, __builtin_amdgcn_rcpf(e + 1.0f), 1.0f);
}
// acc += a.x*w0 + a.y*w1 + a.z*w2 + a.w*w3 (component-wise over 4 cols)
__device__ inline void fma4(float4& acc, const float4 a,
                            const float4 w0, const float4 w1,
                            const float4 w2, const float4 w3) {
    acc.x = fmaf(a.x, w0.x, fmaf(a.y, w1.x, fmaf(a.z, w2.x, fmaf(a.w, w3.x, acc.x))));
    acc.y = fmaf(a.x, w0.y, fmaf(a.y, w1.y, fmaf(a.z, w2.y, fmaf(a.w, w3.y, acc.y))));
    acc.z = fmaf(a.x, w0.z, fmaf(a.y, w1.z, fmaf(a.z, w2.z, fmaf(a.w, w3.z, acc.z))));
    acc.w = fmaf(a.x, w0.w, fmaf(a.y, w1.w, fmaf(a.z, w2.w, fmaf(a.w, w3.w, acc.w))));
}
// expand uint4 (8 bf16) into 8 consecutive fp32 at p
__device__ inline void bf8_to_f32(float* p, uint4 v) {
    p[0] = __uint_as_float(v.x << 16); p[1] = __uint_as_float(v.x & 0xFFFF0000u);
    p[2] = __uint_as_float(v.y << 16); p[3] = __uint_as_float(v.y & 0xFFFF0000u);
    p[4] = __uint_as_float(v.z << 16); p[5] = __uint_as_float(v.z & 0xFFFF0000u);
    p[6] = __uint_as_float(v.w << 16); p[7] = __uint_as_float(v.w & 0xFFFF0000u);
}

// ---------------- CSR build: deterministic 3-level multisplit ----------------

__global__ __launch_bounds__(256) void k_count(const int* __restrict__ dst,
                                               unsigned* __restrict__ cnt) {
    __shared__ unsigned h[NB];
    const int tid = threadIdx.x;
    const long e0 = (long)blockIdx.x * CHUNK;
    for (int i = tid; i < NB; i += 256) h[i] = 0u;
    __syncthreads();
    for (int i = tid; i < CHUNK; i += 256) {
        long e = e0 + i;
        if (e < N_EDGES) atomicAdd(&h[((unsigned)dst[e]) >> 8], 1u);
    }
    __syncthreads();
    for (int b = tid; b < NB; b += 256) cnt[b * NBLK_A + blockIdx.x] = h[b];
}

__global__ __launch_bounds__(512) void k_bucket_scan(unsigned* __restrict__ cnt,
                                                     unsigned* __restrict__ btot) {
    __shared__ unsigned s[512];
    const int tid = threadIdx.x;
    const int b = blockIdx.x;
    unsigned v = (tid < NBLK_A) ? cnt[b * NBLK_A + tid] : 0u;
    s[tid] = v;
    __syncthreads();
    for (int o = 1; o < 512; o <<= 1) {
        unsigned t = (tid >= o) ? s[tid - o] : 0u;
        __syncthreads();
        s[tid] += t;
        __syncthreads();
    }
    if (tid < NBLK_A) cnt[b * NBLK_A + tid] = s[tid] - v;   // exclusive within bucket
    if (tid == NBLK_A - 1) btot[b] = s[tid];
}

__global__ __launch_bounds__(512) void k_scan_bkt(const unsigned* __restrict__ btot,
                                                  unsigned* __restrict__ bktbase) {
    __shared__ unsigned s[512];
    const int tid = threadIdx.x;
    unsigned v = (tid < NB) ? btot[tid] : 0u;
    s[tid] = v;
    __syncthreads();
    for (int o = 1; o < 512; o <<= 1) {
        unsigned t = (tid >= o) ? s[tid - o] : 0u;
        __syncthreads();
        s[tid] += t;
        __syncthreads();
    }
    if (tid < NB) bktbase[tid] = s[tid] - v;
    if (tid == NB - 1) bktbase[NB] = s[tid];   // == E
}

// phase A: LDS multisplit into 391 dst-buckets; binned[pos] = (src<<8)|(dst&255)
__global__ __launch_bounds__(256) void k_bin(const int* __restrict__ src,
                                             const int* __restrict__ dst,
                                             const unsigned* __restrict__ cnt,
                                             const unsigned* __restrict__ bktbase,
                                             unsigned* __restrict__ binned) {
    __shared__ unsigned cntA[NB];
    __shared__ unsigned excl[NB];
    __shared__ unsigned gbase[NB];
    __shared__ unsigned scanbuf[512];
    __shared__ unsigned data[CHUNK];
    const int tid = threadIdx.x;
    const long e0 = (long)blockIdx.x * CHUNK;

    for (int i = tid; i < NB; i += 256) cntA[i] = 0u;
    __syncthreads();
    for (int i = tid; i < CHUNK; i += 256) {
        long e = e0 + i;
        if (e < N_EDGES) atomicAdd(&cntA[((unsigned)dst[e]) >> 8], 1u);
    }
    __syncthreads();
    scanbuf[tid] = (tid < NB) ? cntA[tid] : 0u;
    scanbuf[tid + 256] = (tid + 256 < NB) ? cntA[tid + 256] : 0u;
    __syncthreads();
    for (int o = 1; o < 512; o <<= 1) {
        unsigned v0 = (tid >= o) ? scanbuf[tid - o] : 0u;
        unsigned v1 = (tid + 256 >= o) ? scanbuf[tid + 256 - o] : 0u;
        __syncthreads();
        scanbuf[tid] += v0;
        scanbuf[tid + 256] += v1;
        __syncthreads();
    }
    for (int b = tid; b < NB; b += 256) {
        excl[b] = scanbuf[b] - cntA[b];
        gbase[b] = bktbase[b] + cnt[b * NBLK_A + blockIdx.x];
    }
    __syncthreads();
    for (int i = tid; i < NB; i += 256) cntA[i] = 0u;
    __syncthreads();
    for (int i = tid; i < CHUNK; i += 256) {
        long e = e0 + i;
        if (e < N_EDGES) {
            unsigned d = (unsigned)dst[e];
            unsigned b = d >> 8;
            unsigned slot = excl[b] + atomicAdd(&cntA[b], 1u);
            data[slot] = (((unsigned)src[e]) << 8) | (d & 255u);
        }
    }
    __syncthreads();
    const int w = tid >> 6, lane = tid & 63;
    for (int b = w; b < NB; b += 4) {
        unsigned c = cntA[b];
        unsigned sb = excl[b], gb = gbase[b];
        for (unsigned k = lane; k < c; k += 64)
            binned[gb + k] = data[sb + k];
    }
}

// phase B: per-bucket CSR fill; derives degree/rowptr/dinv from binned
__global__ __launch_bounds__(256) void k_csr_fill2(const unsigned* __restrict__ binned,
                                                   const unsigned* __restrict__ bktbase,
                                                   unsigned* __restrict__ rowptr,
                                                   float* __restrict__ dinv,
                                                   int* __restrict__ ssrc) {
    __shared__ unsigned cnt[256];
    __shared__ unsigned s[256];
    __shared__ unsigned cur[256];
    const int b = blockIdx.x;
    const int tid = threadIdx.x;
    const int n0 = b * 256;
    const unsigned beg = bktbase[b], end = bktbase[b + 1];
    cnt[tid] = 0u;
    __syncthreads();
    for (unsigned i = beg + tid; i < end; i += 256)
        atomicAdd(&cnt[binned[i] & 255u], 1u);
    __syncthreads();
    const unsigned v = cnt[tid];
    s[tid] = v;
    __syncthreads();
    for (int o = 1; o < 256; o <<= 1) {
        unsigned t = (tid >= o) ? s[tid - o] : 0u;
        __syncthreads();
        s[tid] += t;
        __syncthreads();
    }
    const unsigned excl = s[tid] - v;
    const int node = n0 + tid;
    if (node < N_NODES) {
        rowptr[node] = beg + excl;
        dinv[node] = rsqrtf((float)(v + 1u));
        if (node == N_NODES - 1) rowptr[N_NODES] = end;   // == E
    }
    cur[tid] = beg + excl;
    __syncthreads();
    for (unsigned i = beg + tid; i < end; i += 256) {
        unsigned p = binned[i];
        unsigned pos = atomicAdd(&cur[p & 255u], 1u);
        ssrc[pos] = (int)(p >> 8);
    }
}

// ---------------- dense layers ----------------

// xlb[N x 64] (bf16) = (A[N x K fp32] @ W[K x 64]) * dinv[row]; 4x4 reg tile.
template<int K>
__global__ __launch_bounds__(256) void k_gemm_bf(const float* __restrict__ A,
                                                 const float* __restrict__ W,
                                                 const float* __restrict__ dinv,
                                                 ushort_t* __restrict__ C) {
    constexpr int OUT = 64;
    constexpr int BR = 64;
    constexpr int LDA = K + 4;
    __shared__ float Wld[K * OUT];
    __shared__ float Ald[BR * LDA];
    const int tid = threadIdx.x;
    const int row0 = blockIdx.x * BR;
    const int nrows = (N_NODES - row0 < BR) ? (N_NODES - row0) : BR;

    {
        const float4* W4 = reinterpret_cast<const float4*>(W);
        float4* Wl4 = reinterpret_cast<float4*>(Wld);
        for (int i = tid; i < K * OUT / 4; i += 256) Wl4[i] = W4[i];
        const float4* A4 = reinterpret_cast<const float4*>(A + (size_t)row0 * K);
        const int nv = nrows * (K / 4);
        for (int i = tid; i < nv; i += 256) {
            int r = i / (K / 4), q = i % (K / 4);
            *reinterpret_cast<float4*>(&Ald[r * LDA + q * 4]) = A4[i];
        }
    }
    __syncthreads();

    const int tr = tid >> 4;
    const int tc = tid & 15;
    const int r0 = tr * 4;
    float4 acc0 = {0,0,0,0}, acc1 = {0,0,0,0}, acc2v = {0,0,0,0}, acc3 = {0,0,0,0};
#pragma unroll 2
    for (int k4 = 0; k4 < K; k4 += 4) {
        const float4 a0 = *reinterpret_cast<const float4*>(&Ald[(r0 + 0) * LDA + k4]);
        const float4 a1 = *reinterpret_cast<const float4*>(&Ald[(r0 + 1) * LDA + k4]);
        const float4 a2 = *reinterpret_cast<const float4*>(&Ald[(r0 + 2) * LDA + k4]);
        const float4 a3 = *reinterpret_cast<const float4*>(&Ald[(r0 + 3) * LDA + k4]);
        const float4 w0 = *reinterpret_cast<const float4*>(&Wld[(k4 + 0) * OUT + tc * 4]);
        const float4 w1 = *reinterpret_cast<const float4*>(&Wld[(k4 + 1) * OUT + tc * 4]);
        const float4 w2 = *reinterpret_cast<const float4*>(&Wld[(k4 + 2) * OUT + tc * 4]);
        const float4 w3 = *reinterpret_cast<const float4*>(&Wld[(k4 + 3) * OUT + tc * 4]);
        fma4(acc0, a0, w0, w1, w2, w3);
        fma4(acc1, a1, w0, w1, w2, w3);
        fma4(acc2v, a2, w0, w1, w2, w3);
        fma4(acc3, a3, w0, w1, w2, w3);
    }
    float4 accs[4] = {acc0, acc1, acc2v, acc3};
#pragma unroll
    for (int i = 0; i < 4; ++i) {
        const int r = r0 + i;
        if (r < nrows) {
            const float di = dinv[row0 + r];
            ushort4 o;
            o.x = f2bf(accs[i].x * di);
            o.y = f2bf(accs[i].y * di);
            o.z = f2bf(accs[i].z * di);
            o.w = f2bf(accs[i].w * di);
            *reinterpret_cast<ushort4*>(&C[(size_t)(row0 + r) * 64 + tc * 4]) = o;
        }
    }
}

// same GEMM but A input is bf16 (h from previous layer); K=64
__global__ __launch_bounds__(256) void k_gemm_bfin(const ushort_t* __restrict__ A,
                                                   const float* __restrict__ W,
                                                   const float* __restrict__ dinv,
                                                   ushort_t* __restrict__ C) {
    constexpr int K = 64;
    constexpr int OUT = 64;
    constexpr int BR = 64;
    constexpr int LDA = K + 4;
    __shared__ float Wld[K * OUT];
    __shared__ float Ald[BR * LDA];
    const int tid = threadIdx.x;
    const int row0 = blockIdx.x * BR;
    const int nrows = (N_NODES - row0 < BR) ? (N_NODES - row0) : BR;

    {
        const float4* W4 = reinterpret_cast<const float4*>(W);
        float4* Wl4 = reinterpret_cast<float4*>(Wld);
        for (int i = tid; i < K * OUT / 4; i += 256) Wl4[i] = W4[i];
        const uint4* A4 = reinterpret_cast<const uint4*>(A + (size_t)row0 * K);
        const int nv = nrows * 8;   // 8 bf16 per uint4
        for (int i = tid; i < nv; i += 256) {
            int r = i >> 3, q = i & 7;
            bf8_to_f32(&Ald[r * LDA + q * 8], A4[i]);
        }
    }
    __syncthreads();

    const int tr = tid >> 4;
    const int tc = tid & 15;
    const int r0 = tr * 4;
    float4 acc0 = {0,0,0,0}, acc1 = {0,0,0,0}, acc2v = {0,0,0,0}, acc3 = {0,0,0,0};
#pragma unroll 2
    for (int k4 = 0; k4 < K; k4 += 4) {
        const float4 a0 = *reinterpret_cast<const float4*>(&Ald[(r0 + 0) * LDA + k4]);
        const float4 a1 = *reinterpret_cast<const float4*>(&Ald[(r0 + 1) * LDA + k4]);
        const float4 a2 = *reinterpret_cast<const float4*>(&Ald[(r0 + 2) * LDA + k4]);
        const float4 a3 = *reinterpret_cast<const float4*>(&Ald[(r0 + 3) * LDA + k4]);
        const float4 w0 = *reinterpret_cast<const float4*>(&Wld[(k4 + 0) * OUT + tc * 4]);
        const float4 w1 = *reinterpret_cast<const float4*>(&Wld[(k4 + 1) * OUT + tc * 4]);
        const float4 w2 = *reinterpret_cast<const float4*>(&Wld[(k4 + 2) * OUT + tc * 4]);
        const float4 w3 = *reinterpret_cast<const float4*>(&Wld[(k4 + 3) * OUT + tc * 4]);
        fma4(acc0, a0, w0, w1, w2, w3);
        fma4(acc1, a1, w0, w1, w2, w3);
        fma4(acc2v, a2, w0, w1, w2, w3);
        fma4(acc3, a3, w0, w1, w2, w3);
    }
    float4 accs[4] = {acc0, acc1, acc2v, acc3};
#pragma unroll
    for (int i = 0; i < 4; ++i) {
        const int r = r0 + i;
        if (r < nrows) {
            const float di = dinv[row0 + r];
            ushort4 o;
            o.x = f2bf(accs[i].x * di);
            o.y = f2bf(accs[i].y * di);
            o.z = f2bf(accs[i].z * di);
            o.w = f2bf(accs[i].w * di);
            *reinterpret_cast<ushort4*>(&C[(size_t)(row0 + r) * 64 + tc * 4]) = o;
        }
    }
}

// one node per 64-lane wave; 8 lane-groups x 8 lanes; lane loads uint4 = 8 bf16.
// 16 edge-gathers in flight per wave; output h packed bf16.
__global__ __launch_bounds__(256) void k_agg(const ushort_t* __restrict__ xlb,
                                             const float* __restrict__ dinv,
                                             const unsigned* __restrict__ rowptr,
                                             const int* __restrict__ ssrc,
                                             const float* __restrict__ bias,
                                             ushort_t* __restrict__ hb) {
    const int node = blockIdx.x * 4 + (threadIdx.x >> 6);
    const int lane = threadIdx.x & 63;
    const int g = lane >> 3;        // edge group 0..7
    const int l = lane & 7;         // feature octet 0..7 (features l*8..l*8+7)
    const uint4* xb4 = reinterpret_cast<const uint4*>(xlb);  // 8 uint4 per row

    const unsigned beg = rowptr[node], end = rowptr[node + 1];
    float a[8] = {0.f,0.f,0.f,0.f,0.f,0.f,0.f,0.f};
    float b[8] = {0.f,0.f,0.f,0.f,0.f,0.f,0.f,0.f};
    if (g == 0) {   // self-loop
        const uint4 v = xb4[(size_t)node * 8 + l];
        acc2(a[0], a[1], v.x); acc2(a[2], a[3], v.y);
        acc2(a[4], a[5], v.z); acc2(a[6], a[7], v.w);
    }
    unsigned j = beg + g;
    for (; j + 8 < end; j += 16) {
        const int s0 = ssrc[j];
        const int s1 = ssrc[j + 8];
        const uint4 v0 = xb4[(size_t)s0 * 8 + l];
        const uint4 v1 = xb4[(size_t)s1 * 8 + l];
        acc2(a[0], a[1], v0.x); acc2(a[2], a[3], v0.y);
        acc2(a[4], a[5], v0.z); acc2(a[6], a[7], v0.w);
        acc2(b[0], b[1], v1.x); acc2(b[2], b[3], v1.y);
        acc2(b[4], b[5], v1.z); acc2(b[6], b[7], v1.w);
    }
    if (j < end) {
        const uint4 v = xb4[(size_t)ssrc[j] * 8 + l];
        acc2(a[0], a[1], v.x); acc2(a[2], a[3], v.y);
        acc2(a[4], a[5], v.z); acc2(a[6], a[7], v.w);
    }
#pragma unroll
    for (int i = 0; i < 8; ++i) a[i] += b[i];
#pragma unroll
    for (int i = 0; i < 8; ++i) {
        a[i] += __shfl_xor(a[i], 8);
        a[i] += __shfl_xor(a[i], 16);
        a[i] += __shfl_xor(a[i], 32);
    }
    if (g == 0) {
        const float di = dinv[node];
        const float4 b0 = reinterpret_cast<const float4*>(bias)[l * 2];
        const float4 b1 = reinterpret_cast<const float4*>(bias)[l * 2 + 1];
        float r0 = fast_tanh(fmaf(a[0], di, b0.x));
        float r1 = fast_tanh(fmaf(a[1], di, b0.y));
        float r2 = fast_tanh(fmaf(a[2], di, b0.z));
        float r3 = fast_tanh(fmaf(a[3], di, b0.w));
        float r4 = fast_tanh(fmaf(a[4], di, b1.x));
        float r5 = fast_tanh(fmaf(a[5], di, b1.y));
        float r6 = fast_tanh(fmaf(a[6], di, b1.z));
        float r7 = fast_tanh(fmaf(a[7], di, b1.w));
        uint4 o;
        o.x = (unsigned)f2bf(r0) | ((unsigned)f2bf(r1) << 16);
        o.y = (unsigned)f2bf(r2) | ((unsigned)f2bf(r3) << 16);
        o.z = (unsigned)f2bf(r4) | ((unsigned)f2bf(r5) << 16);
        o.w = (unsigned)f2bf(r6) | ((unsigned)f2bf(r7) << 16);
        reinterpret_cast<uint4*>(hb)[(size_t)node * 8 + l] = o;
    }
}

// fused FC stack (input bf16), register-tiled fp32, controlled unrolling, fast_tanh.
__global__ __launch_bounds__(256, 4) void k_fc(const ushort_t* __restrict__ h2,
                                               const float* __restrict__ fW0, const float* __restrict__ fb0,
                                               const float* __restrict__ fW1, const float* __restrict__ fb1,
                                               const float* __restrict__ fW2, const float* __restrict__ fb2,
                                               float* __restrict__ out) {
    constexpr int BR = 32;
    constexpr int LDH = 68;
    __shared__ float W0[64 * 64];
    __shared__ float W1[64 * 32];
    __shared__ float Hin[BR * LDH];
    __shared__ float Ht[BR * LDH];
    __shared__ float Hs[BR * 33];
    __shared__ float W2s[33];
    const int tid = threadIdx.x;
    {
        const float4* w04 = reinterpret_cast<const float4*>(fW0);
        float4* W04 = reinterpret_cast<float4*>(W0);
        for (int i = tid; i < 64 * 16; i += 256) W04[i] = w04[i];
        const float4* w14 = reinterpret_cast<const float4*>(fW1);
        float4* W14 = reinterpret_cast<float4*>(W1);
        for (int i = tid; i < 64 * 8; i += 256) W14[i] = w14[i];
        if (tid < 32) W2s[tid] = fW2[tid];
        if (tid == 32) W2s[32] = fb2[0];
    }
    const long row0 = (long)blockIdx.x * BR;
    {
        const uint4* H4 = reinterpret_cast<const uint4*>(h2 + row0 * 64);
        // BR*64 bf16 = BR*8 uint4 = 256 loads
        if (tid < BR * 8) {
            int r = tid >> 3, q = tid & 7;
            bf8_to_f32(&Hin[r * LDH + q * 8], H4[tid]);
        }
    }
    __syncthreads();

    // ---- fc0: 32x64, tile 2 rows x 4 cols, 256 threads ----
    {
        const int rp = tid >> 4;
        const int cq = tid & 15;
        const int r0 = rp * 2, r1 = r0 + 1;
        const float4 bias = reinterpret_cast<const float4*>(fb0)[cq];
        float4 acc0 = bias, acc1 = bias;
#pragma unroll 2
        for (int k4 = 0; k4 < 64; k4 += 4) {
            const float4 a0 = *reinterpret_cast<const float4*>(&Hin[r0 * LDH + k4]);
            const float4 a1 = *reinterpret_cast<const float4*>(&Hin[r1 * LDH + k4]);
            const float4 w0 = *reinterpret_cast<const float4*>(&W0[(k4 + 0) * 64 + cq * 4]);
            const float4 w1 = *reinterpret_cast<const float4*>(&W0[(k4 + 1) * 64 + cq * 4]);
            const float4 w2 = *reinterpret_cast<const float4*>(&W0[(k4 + 2) * 64 + cq * 4]);
            const float4 w3 = *reinterpret_cast<const float4*>(&W0[(k4 + 3) * 64 + cq * 4]);
            fma4(acc0, a0, w0, w1, w2, w3);
            fma4(acc1, a1, w0, w1, w2, w3);
        }
        float4 t0, t1;
        t0.x = fast_tanh(acc0.x); t0.y = fast_tanh(acc0.y);
        t0.z = fast_tanh(acc0.z); t0.w = fast_tanh(acc0.w);
        t1.x = fast_tanh(acc1.x); t1.y = fast_tanh(acc1.y);
        t1.z = fast_tanh(acc1.z); t1.w = fast_tanh(acc1.w);
        *reinterpret_cast<float4*>(&Ht[r0 * LDH + cq * 4]) = t0;
        *reinterpret_cast<float4*>(&Ht[r1 * LDH + cq * 4]) = t1;
    }
    __syncthreads();

    // ---- fc1: 32x32, tile 1 row x 4 cols, 256 threads ----
    {
        const int r = tid >> 3;
        const int cq = tid & 7;
        const float4 bias = reinterpret_cast<const float4*>(fb1)[cq];
        float4 acc0 = bias;
#pragma unroll 2
        for (int k4 = 0; k4 < 64; k4 += 4) {
            const float4 a0 = *reinterpret_cast<const float4*>(&Ht[r * LDH + k4]);
            const float4 w0 = *reinterpret_cast<const float4*>(&W1[(k4 + 0) * 32 + cq * 4]);
            const float4 w1 = *reinterpret_cast<const float4*>(&W1[(k4 + 1) * 32 + cq * 4]);
            const float4 w2 = *reinterpret_cast<const float4*>(&W1[(k4 + 2) * 32 + cq * 4]);
            const float4 w3 = *reinterpret_cast<const float4*>(&W1[(k4 + 3) * 32 + cq * 4]);
            fma4(acc0, a0, w0, w1, w2, w3);
        }
        Hs[r * 33 + cq * 4 + 0] = fast_tanh(acc0.x);
        Hs[r * 33 + cq * 4 + 1] = fast_tanh(acc0.y);
        Hs[r * 33 + cq * 4 + 2] = fast_tanh(acc0.z);
        Hs[r * 33 + cq * 4 + 3] = fast_tanh(acc0.w);
    }
    __syncthreads();

    // ---- fc2: 32 -> 1 ----
    if (tid < BR) {
        float a = W2s[32];
        for (int k = 0; k < 32; ++k) a = fmaf(Hs[tid * 33 + k], W2s[k], a);
        out[row0 + tid] = a;
    }
}

// ---------------- launch ----------------

extern "C" void kernel_launch(void* const* d_in, const int* in_sizes, int n_in,
                              void* d_out, int out_size, void* d_ws, size_t ws_size,
                              hipStream_t stream) {
    const float* x    = (const float*)d_in[0];
    const int*   eidx = (const int*)d_in[1];
    const float* cW0  = (const float*)d_in[2];
    const float* cb0  = (const float*)d_in[3];
    const float* cW1  = (const float*)d_in[4];
    const float* cb1  = (const float*)d_in[5];
    const float* fW0  = (const float*)d_in[6];
    const float* fb0  = (const float*)d_in[7];
    const float* fW1  = (const float*)d_in[8];
    const float* fb1  = (const float*)d_in[9];
    const float* fW2  = (const float*)d_in[10];
    const float* fb2  = (const float*)d_in[11];
    float* out = (float*)d_out;

    const int* src = eidx;
    const int* dst = eidx + N_EDGES;

    char* ws = (char*)d_ws;
    unsigned* rowptr  = (unsigned*)(ws);                  // 400,004 B
    float*    dinv    = (float*)   (ws + 400016);         // 400,000 B
    unsigned* cnt     = (unsigned*)(ws + 800016);         // 611,524 B
    unsigned* btot    = (unsigned*)(ws + 1411552);        // 1,564 B
    unsigned* bktbase = (unsigned*)(ws + 1413120);        // 1,568 B
    int*      ssrc    = (int*)     (ws + 1414688);        // 6,400,000 B
    ushort_t* xlb     = (ushort_t*)(ws + 7814688);        // 12,800,000 B
    unsigned* binned  = (unsigned*)(ws + 20614688);       // 6,400,000 B
    ushort_t* hb      = (ushort_t*)(ws + 27014688);       // 12,800,000 B -> ends 39,814,688

    const int gRow = N_NODES / 32;              // 3125 (k_fc)
    const int gGemm = (N_NODES + 63) / 64;      // 1563
    const int gAgg = N_NODES / 4;               // 25000

    // CSR build (deterministic, no global fine-grained atomics)
    k_count<<<NBLK_A, 256, 0, stream>>>(dst, cnt);
    k_bucket_scan<<<NB, 512, 0, stream>>>(cnt, btot);
    k_scan_bkt<<<1, 512, 0, stream>>>(btot, bktbase);
    k_bin<<<NBLK_A, 256, 0, stream>>>(src, dst, cnt, bktbase, binned);
    k_csr_fill2<<<NB, 256, 0, stream>>>(binned, bktbase, rowptr, dinv, ssrc);

    // conv0: x (fp32) -> xlb (bf16, pre-scaled)
    k_gemm_bf<128><<<gGemm, 256, 0, stream>>>(x, cW0, dinv, xlb);
    k_agg<<<gAgg, 256, 0, stream>>>(xlb, dinv, rowptr, ssrc, cb0, hb);
    // conv1: hb (bf16) -> xlb (bf16, pre-scaled)
    k_gemm_bfin<<<gGemm, 256, 0, stream>>>(hb, cW1, dinv, xlb);
    k_agg<<<gAgg, 256, 0, stream>>>(xlb, dinv, rowptr, ssrc, cb1, hb);
    // fc stack: hb (bf16) -> out
    k_fc<<<gRow, 256, 0, stream>>>(hb, fW0, fb0, fW1, fb1, fW2, fb2, out);
}

// Round 12
// 231.003 us; speedup vs baseline: 6.6624x; 1.0816x over previous
//
#include <hip/hip_runtime.h>
#include <math.h>

#define N_NODES 100000
#define N_EDGES 1600000
#define NB     391   // buckets of 256 nodes
#define CHUNK  4096  // edges per chunk block
#define NBLK_A 391   // ceil(E/CHUNK)
#define GEMM0_BLOCKS 1563   // ceil(N/64)

typedef unsigned short ushort_t;

__device__ inline unsigned short f2bf(float f) {
    unsigned u = __float_as_uint(f);
    unsigned r = (u + 0x7FFFu + ((u >> 16) & 1u)) >> 16;
    return (unsigned short)r;
}
// accumulate 2 packed bf16 into 2 fp32 (unit scale)
__device__ inline void acc2(float& a0, float& a1, unsigned u) {
    a0 += __uint_as_float(u << 16);
    a1 += __uint_as_float(u & 0xFFFF0000u);
}
// accumulate 2 packed bf16 scaled by s
__device__ inline void acc2s(float& a0, float& a1, unsigned u, float s) {
    a0 = fmaf(__uint_as_float(u << 16), s, a0);
    a1 = fmaf(__uint_as_float(u & 0xFFFF0000u), s, a1);
}
// tanh(x) = 1 - 2/(exp(2x)+1)
__device__ inline float fast_tanh(float x) {
    float e = __expf(2.0f * x);
    return fmaf(-2.0f, __builtin_amdgcn_rcpf(e + 1.0f), 1.0f);
}
__device__ inline void fma4(float4& acc, const float4 a,
                            const float4 w0, const float4 w1,
                            const float4 w2, const float4 w3) {
    acc.x = fmaf(a.x, w0.x, fmaf(a.y, w1.x, fmaf(a.z, w2.x, fmaf(a.w, w3.x, acc.x))));
    acc.y = fmaf(a.x, w0.y, fmaf(a.y, w1.y, fmaf(a.z, w2.y, fmaf(a.w, w3.y, acc.y))));
    acc.z = fmaf(a.x, w0.z, fmaf(a.y, w1.z, fmaf(a.z, w2.z, fmaf(a.w, w3.z, acc.z))));
    acc.w = fmaf(a.x, w0.w, fmaf(a.y, w1.w, fmaf(a.z, w2.w, fmaf(a.w, w3.w, acc.w))));
}
__device__ inline void bf8_to_f32(float* p, uint4 v) {
    p[0] = __uint_as_float(v.x << 16); p[1] = __uint_as_float(v.x & 0xFFFF0000u);
    p[2] = __uint_as_float(v.y << 16); p[3] = __uint_as_float(v.y & 0xFFFF0000u);
    p[4] = __uint_as_float(v.z << 16); p[5] = __uint_as_float(v.z & 0xFFFF0000u);
    p[6] = __uint_as_float(v.w << 16); p[7] = __uint_as_float(v.w & 0xFFFF0000u);
}

// ---------------- fused conv0 GEMM (unscaled) + coarse count ----------------
// blocks [0, GEMM0_BLOCKS): xlb[N x 64] (bf16) = x[N x 128] @ cW0  (NO dinv)
// blocks [GEMM0_BLOCKS, +NBLK_A): per-chunk coarse histogram -> cnt matrix
__global__ __launch_bounds__(256) void k_gemm0_count(const float* __restrict__ A,
                                                     const float* __restrict__ W,
                                                     ushort_t* __restrict__ C,
                                                     const int* __restrict__ dst,
                                                     unsigned* __restrict__ cnt) {
    constexpr int K = 128, OUT = 64, BR = 64, LDA = K + 4;
    __shared__ __align__(16) char smem[(K * OUT + BR * LDA) * 4];
    const int tid = threadIdx.x;

    if (blockIdx.x >= GEMM0_BLOCKS) {
        // ---- count path ----
        unsigned* h = (unsigned*)smem;
        const int cb = blockIdx.x - GEMM0_BLOCKS;
        const long e0 = (long)cb * CHUNK;
        for (int i = tid; i < NB; i += 256) h[i] = 0u;
        __syncthreads();
        for (int i = tid; i < CHUNK; i += 256) {
            long e = e0 + i;
            if (e < N_EDGES) atomicAdd(&h[((unsigned)dst[e]) >> 8], 1u);
        }
        __syncthreads();
        for (int b = tid; b < NB; b += 256) cnt[b * NBLK_A + cb] = h[b];
        return;
    }

    // ---- GEMM path ----
    float* Wld = (float*)smem;
    float* Ald = Wld + K * OUT;
    const int row0 = blockIdx.x * BR;
    const int nrows = (N_NODES - row0 < BR) ? (N_NODES - row0) : BR;
    {
        const float4* W4 = reinterpret_cast<const float4*>(W);
        float4* Wl4 = reinterpret_cast<float4*>(Wld);
        for (int i = tid; i < K * OUT / 4; i += 256) Wl4[i] = W4[i];
        const float4* A4 = reinterpret_cast<const float4*>(A + (size_t)row0 * K);
        const int nv = nrows * (K / 4);
        for (int i = tid; i < nv; i += 256) {
            int r = i / (K / 4), q = i % (K / 4);
            *reinterpret_cast<float4*>(&Ald[r * LDA + q * 4]) = A4[i];
        }
    }
    __syncthreads();

    const int tr = tid >> 4, tc = tid & 15;
    const int r0 = tr * 4;
    float4 acc0 = {0,0,0,0}, acc1 = {0,0,0,0}, acc2v = {0,0,0,0}, acc3 = {0,0,0,0};
#pragma unroll 2
    for (int k4 = 0; k4 < K; k4 += 4) {
        const float4 a0 = *reinterpret_cast<const float4*>(&Ald[(r0 + 0) * LDA + k4]);
        const float4 a1 = *reinterpret_cast<const float4*>(&Ald[(r0 + 1) * LDA + k4]);
        const float4 a2 = *reinterpret_cast<const float4*>(&Ald[(r0 + 2) * LDA + k4]);
        const float4 a3 = *reinterpret_cast<const float4*>(&Ald[(r0 + 3) * LDA + k4]);
        const float4 w0 = *reinterpret_cast<const float4*>(&Wld[(k4 + 0) * OUT + tc * 4]);
        const float4 w1 = *reinterpret_cast<const float4*>(&Wld[(k4 + 1) * OUT + tc * 4]);
        const float4 w2 = *reinterpret_cast<const float4*>(&Wld[(k4 + 2) * OUT + tc * 4]);
        const float4 w3 = *reinterpret_cast<const float4*>(&Wld[(k4 + 3) * OUT + tc * 4]);
        fma4(acc0, a0, w0, w1, w2, w3);
        fma4(acc1, a1, w0, w1, w2, w3);
        fma4(acc2v, a2, w0, w1, w2, w3);
        fma4(acc3, a3, w0, w1, w2, w3);
    }
    float4 accs[4] = {acc0, acc1, acc2v, acc3};
#pragma unroll
    for (int i = 0; i < 4; ++i) {
        const int r = r0 + i;
        if (r < nrows) {
            ushort4 o;
            o.x = f2bf(accs[i].x); o.y = f2bf(accs[i].y);
            o.z = f2bf(accs[i].z); o.w = f2bf(accs[i].w);
            *reinterpret_cast<ushort4*>(&C[(size_t)(row0 + r) * 64 + tc * 4]) = o;
        }
    }
}

// ---------------- CSR build (rest) ----------------

__global__ __launch_bounds__(512) void k_bucket_scan(unsigned* __restrict__ cnt,
                                                     unsigned* __restrict__ btot) {
    __shared__ unsigned s[512];
    const int tid = threadIdx.x;
    const int b = blockIdx.x;
    unsigned v = (tid < NBLK_A) ? cnt[b * NBLK_A + tid] : 0u;
    s[tid] = v;
    __syncthreads();
    for (int o = 1; o < 512; o <<= 1) {
        unsigned t = (tid >= o) ? s[tid - o] : 0u;
        __syncthreads();
        s[tid] += t;
        __syncthreads();
    }
    if (tid < NBLK_A) cnt[b * NBLK_A + tid] = s[tid] - v;
    if (tid == NBLK_A - 1) btot[b] = s[tid];
}

__global__ __launch_bounds__(512) void k_scan_bkt(const unsigned* __restrict__ btot,
                                                  unsigned* __restrict__ bktbase) {
    __shared__ unsigned s[512];
    const int tid = threadIdx.x;
    unsigned v = (tid < NB) ? btot[tid] : 0u;
    s[tid] = v;
    __syncthreads();
    for (int o = 1; o < 512; o <<= 1) {
        unsigned t = (tid >= o) ? s[tid - o] : 0u;
        __syncthreads();
        s[tid] += t;
        __syncthreads();
    }
    if (tid < NB) bktbase[tid] = s[tid] - v;
    if (tid == NB - 1) bktbase[NB] = s[tid];   // == E
}

// phase A: LDS multisplit into 391 dst-buckets; parallel coalesced flush
__global__ __launch_bounds__(256) void k_bin(const int* __restrict__ src,
                                             const int* __restrict__ dst,
                                             const unsigned* __restrict__ cnt,
                                             const unsigned* __restrict__ bktbase,
                                             unsigned* __restrict__ binned) {
    __shared__ unsigned cntA[NB];
    __shared__ unsigned excl[NB];
    __shared__ unsigned gbase[NB];
    __shared__ unsigned scanbuf[512];
    __shared__ unsigned data[CHUNK];
    __shared__ ushort_t bkt16[CHUNK];
    const int tid = threadIdx.x;
    const long e0 = (long)blockIdx.x * CHUNK;
    const int n = (N_EDGES - e0 < CHUNK) ? (int)(N_EDGES - e0) : CHUNK;

    for (int i = tid; i < NB; i += 256) cntA[i] = 0u;
    __syncthreads();
    for (int i = tid; i < n; i += 256)
        atomicAdd(&cntA[((unsigned)dst[e0 + i]) >> 8], 1u);
    __syncthreads();
    scanbuf[tid] = (tid < NB) ? cntA[tid] : 0u;
    scanbuf[tid + 256] = (tid + 256 < NB) ? cntA[tid + 256] : 0u;
    __syncthreads();
    for (int o = 1; o < 512; o <<= 1) {
        unsigned v0 = (tid >= o) ? scanbuf[tid - o] : 0u;
        unsigned v1 = (tid + 256 >= o) ? scanbuf[tid + 256 - o] : 0u;
        __syncthreads();
        scanbuf[tid] += v0;
        scanbuf[tid + 256] += v1;
        __syncthreads();
    }
    for (int b = tid; b < NB; b += 256) {
        excl[b] = scanbuf[b] - cntA[b];
        gbase[b] = bktbase[b] + cnt[b * NBLK_A + blockIdx.x];
    }
    __syncthreads();
    for (int i = tid; i < NB; i += 256) cntA[i] = 0u;
    __syncthreads();
    for (int i = tid; i < n; i += 256) {
        long e = e0 + i;
        unsigned d = (unsigned)dst[e];
        unsigned b = d >> 8;
        unsigned slot = excl[b] + atomicAdd(&cntA[b], 1u);
        data[slot] = (((unsigned)src[e]) << 8) | (d & 255u);
        bkt16[slot] = (ushort_t)b;
    }
    __syncthreads();
    // parallel flush: slot order == ascending bucket, coalesced global writes
    for (int i = tid; i < n; i += 256) {
        unsigned b = bkt16[i];
        binned[gbase[b] + (unsigned)i - excl[b]] = data[i];
    }
}

// phase B: per-bucket CSR fill; derives degree/rowptr/dinv from binned
__global__ __launch_bounds__(256) void k_csr_fill2(const unsigned* __restrict__ binned,
                                                   const unsigned* __restrict__ bktbase,
                                                   unsigned* __restrict__ rowptr,
                                                   float* __restrict__ dinv,
                                                   int* __restrict__ ssrc) {
    __shared__ unsigned cnt[256];
    __shared__ unsigned s[256];
    __shared__ unsigned cur[256];
    const int b = blockIdx.x;
    const int tid = threadIdx.x;
    const int n0 = b * 256;
    const unsigned beg = bktbase[b], end = bktbase[b + 1];
    cnt[tid] = 0u;
    __syncthreads();
    for (unsigned i = beg + tid; i < end; i += 256)
        atomicAdd(&cnt[binned[i] & 255u], 1u);
    __syncthreads();
    const unsigned v = cnt[tid];
    s[tid] = v;
    __syncthreads();
    for (int o = 1; o < 256; o <<= 1) {
        unsigned t = (tid >= o) ? s[tid - o] : 0u;
        __syncthreads();
        s[tid] += t;
        __syncthreads();
    }
    const unsigned excl = s[tid] - v;
    const int node = n0 + tid;
    if (node < N_NODES) {
        rowptr[node] = beg + excl;
        dinv[node] = rsqrtf((float)(v + 1u));
        if (node == N_NODES - 1) rowptr[N_NODES] = end;   // == E
    }
    cur[tid] = beg + excl;
    __syncthreads();
    for (unsigned i = beg + tid; i < end; i += 256) {
        unsigned p = binned[i];
        unsigned pos = atomicAdd(&cur[p & 255u], 1u);
        ssrc[pos] = (int)(p >> 8);
    }
}

// ---------------- dense layers ----------------

// conv1 GEMM: A bf16 in, output scaled by dinv[row]; K=64
__global__ __launch_bounds__(256) void k_gemm_bfin(const ushort_t* __restrict__ A,
                                                   const float* __restrict__ W,
                                                   const float* __restrict__ dinv,
                                                   ushort_t* __restrict__ C) {
    constexpr int K = 64, OUT = 64, BR = 64, LDA = K + 4;
    __shared__ float Wld[K * OUT];
    __shared__ float Ald[BR * LDA];
    const int tid = threadIdx.x;
    const int row0 = blockIdx.x * BR;
    const int nrows = (N_NODES - row0 < BR) ? (N_NODES - row0) : BR;

    {
        const float4* W4 = reinterpret_cast<const float4*>(W);
        float4* Wl4 = reinterpret_cast<float4*>(Wld);
        for (int i = tid; i < K * OUT / 4; i += 256) Wl4[i] = W4[i];
        const uint4* A4 = reinterpret_cast<const uint4*>(A + (size_t)row0 * K);
        const int nv = nrows * 8;
        for (int i = tid; i < nv; i += 256) {
            int r = i >> 3, q = i & 7;
            bf8_to_f32(&Ald[r * LDA + q * 8], A4[i]);
        }
    }
    __syncthreads();

    const int tr = tid >> 4, tc = tid & 15;
    const int r0 = tr * 4;
    float4 acc0 = {0,0,0,0}, acc1 = {0,0,0,0}, acc2v = {0,0,0,0}, acc3 = {0,0,0,0};
#pragma unroll 2
    for (int k4 = 0; k4 < K; k4 += 4) {
        const float4 a0 = *reinterpret_cast<const float4*>(&Ald[(r0 + 0) * LDA + k4]);
        const float4 a1 = *reinterpret_cast<const float4*>(&Ald[(r0 + 1) * LDA + k4]);
        const float4 a2 = *reinterpret_cast<const float4*>(&Ald[(r0 + 2) * LDA + k4]);
        const float4 a3 = *reinterpret_cast<const float4*>(&Ald[(r0 + 3) * LDA + k4]);
        const float4 w0 = *reinterpret_cast<const float4*>(&Wld[(k4 + 0) * OUT + tc * 4]);
        const float4 w1 = *reinterpret_cast<const float4*>(&Wld[(k4 + 1) * OUT + tc * 4]);
        const float4 w2 = *reinterpret_cast<const float4*>(&Wld[(k4 + 2) * OUT + tc * 4]);
        const float4 w3 = *reinterpret_cast<const float4*>(&Wld[(k4 + 3) * OUT + tc * 4]);
        fma4(acc0, a0, w0, w1, w2, w3);
        fma4(acc1, a1, w0, w1, w2, w3);
        fma4(acc2v, a2, w0, w1, w2, w3);
        fma4(acc3, a3, w0, w1, w2, w3);
    }
    float4 accs[4] = {acc0, acc1, acc2v, acc3};
#pragma unroll
    for (int i = 0; i < 4; ++i) {
        const int r = r0 + i;
        if (r < nrows) {
            const float di = dinv[row0 + r];
            ushort4 o;
            o.x = f2bf(accs[i].x * di);
            o.y = f2bf(accs[i].y * di);
            o.z = f2bf(accs[i].z * di);
            o.w = f2bf(accs[i].w * di);
            *reinterpret_cast<ushort4*>(&C[(size_t)(row0 + r) * 64 + tc * 4]) = o;
        }
    }
}

// one node per 64-lane wave; 8 lane-groups x 8 lanes; lane loads uint4 = 8 bf16.
// SCALED_IN: xlb pre-scaled by dinv[row] (unit accumulate).
// !SCALED_IN: xlb unscaled; accumulate with per-edge dinv[s] FMA.
template<bool SCALED_IN>
__global__ __launch_bounds__(256) void k_agg(const ushort_t* __restrict__ xlb,
                                             const float* __restrict__ dinv,
                                             const unsigned* __restrict__ rowptr,
                                             const int* __restrict__ ssrc,
                                             const float* __restrict__ bias,
                                             ushort_t* __restrict__ hb) {
    const int node = blockIdx.x * 4 + (threadIdx.x >> 6);
    const int lane = threadIdx.x & 63;
    const int g = lane >> 3;
    const int l = lane & 7;
    const uint4* xb4 = reinterpret_cast<const uint4*>(xlb);

    const unsigned beg = rowptr[node], end = rowptr[node + 1];
    float a[8] = {0.f,0.f,0.f,0.f,0.f,0.f,0.f,0.f};
    float b[8] = {0.f,0.f,0.f,0.f,0.f,0.f,0.f,0.f};
    if (g == 0) {   // self-loop
        const uint4 v = xb4[(size_t)node * 8 + l];
        if (SCALED_IN) {
            acc2(a[0], a[1], v.x); acc2(a[2], a[3], v.y);
            acc2(a[4], a[5], v.z); acc2(a[6], a[7], v.w);
        } else {
            const float dn = dinv[node];
            acc2s(a[0], a[1], v.x, dn); acc2s(a[2], a[3], v.y, dn);
            acc2s(a[4], a[5], v.z, dn); acc2s(a[6], a[7], v.w, dn);
        }
    }
    unsigned j = beg + g;
    for (; j + 8 < end; j += 16) {
        const int s0 = ssrc[j];
        const int s1 = ssrc[j + 8];
        const uint4 v0 = xb4[(size_t)s0 * 8 + l];
        const uint4 v1 = xb4[(size_t)s1 * 8 + l];
        if (SCALED_IN) {
            acc2(a[0], a[1], v0.x); acc2(a[2], a[3], v0.y);
            acc2(a[4], a[5], v0.z); acc2(a[6], a[7], v0.w);
            acc2(b[0], b[1], v1.x); acc2(b[2], b[3], v1.y);
            acc2(b[4], b[5], v1.z); acc2(b[6], b[7], v1.w);
        } else {
            const float d0 = dinv[s0];
            const float d1 = dinv[s1];
            acc2s(a[0], a[1], v0.x, d0); acc2s(a[2], a[3], v0.y, d0);
            acc2s(a[4], a[5], v0.z, d0); acc2s(a[6], a[7], v0.w, d0);
            acc2s(b[0], b[1], v1.x, d1); acc2s(b[2], b[3], v1.y, d1);
            acc2s(b[4], b[5], v1.z, d1); acc2s(b[6], b[7], v1.w, d1);
        }
    }
    if (j < end) {
        const int s0 = ssrc[j];
        const uint4 v = xb4[(size_t)s0 * 8 + l];
        if (SCALED_IN) {
            acc2(a[0], a[1], v.x); acc2(a[2], a[3], v.y);
            acc2(a[4], a[5], v.z); acc2(a[6], a[7], v.w);
        } else {
            const float d0 = dinv[s0];
            acc2s(a[0], a[1], v.x, d0); acc2s(a[2], a[3], v.y, d0);
            acc2s(a[4], a[5], v.z, d0); acc2s(a[6], a[7], v.w, d0);
        }
    }
#pragma unroll
    for (int i = 0; i < 8; ++i) a[i] += b[i];
#pragma unroll
    for (int i = 0; i < 8; ++i) {
        a[i] += __shfl_xor(a[i], 8);
        a[i] += __shfl_xor(a[i], 16);
        a[i] += __shfl_xor(a[i], 32);
    }
    if (g == 0) {
        const float di = dinv[node];
        const float4 b0 = reinterpret_cast<const float4*>(bias)[l * 2];
        const float4 b1 = reinterpret_cast<const float4*>(bias)[l * 2 + 1];
        float r0 = fast_tanh(fmaf(a[0], di, b0.x));
        float r1 = fast_tanh(fmaf(a[1], di, b0.y));
        float r2 = fast_tanh(fmaf(a[2], di, b0.z));
        float r3 = fast_tanh(fmaf(a[3], di, b0.w));
        float r4 = fast_tanh(fmaf(a[4], di, b1.x));
        float r5 = fast_tanh(fmaf(a[5], di, b1.y));
        float r6 = fast_tanh(fmaf(a[6], di, b1.z));
        float r7 = fast_tanh(fmaf(a[7], di, b1.w));
        uint4 o;
        o.x = (unsigned)f2bf(r0) | ((unsigned)f2bf(r1) << 16);
        o.y = (unsigned)f2bf(r2) | ((unsigned)f2bf(r3) << 16);
        o.z = (unsigned)f2bf(r4) | ((unsigned)f2bf(r5) << 16);
        o.w = (unsigned)f2bf(r6) | ((unsigned)f2bf(r7) << 16);
        reinterpret_cast<uint4*>(hb)[(size_t)node * 8 + l] = o;
    }
}

// fused FC stack (input bf16), register-tiled fp32, controlled unrolling, fast_tanh.
__global__ __launch_bounds__(256, 4) void k_fc(const ushort_t* __restrict__ h2,
                                               const float* __restrict__ fW0, const float* __restrict__ fb0,
                                               const float* __restrict__ fW1, const float* __restrict__ fb1,
                                               const float* __restrict__ fW2, const float* __restrict__ fb2,
                                               float* __restrict__ out) {
    constexpr int BR = 32;
    constexpr int LDH = 68;
    __shared__ float W0[64 * 64];
    __shared__ float W1[64 * 32];
    __shared__ float Hin[BR * LDH];
    __shared__ float Ht[BR * LDH];
    __shared__ float Hs[BR * 33];
    __shared__ float W2s[33];
    const int tid = threadIdx.x;
    {
        const float4* w04 = reinterpret_cast<const float4*>(fW0);
        float4* W04 = reinterpret_cast<float4*>(W0);
        for (int i = tid; i < 64 * 16; i += 256) W04[i] = w04[i];
        const float4* w14 = reinterpret_cast<const float4*>(fW1);
        float4* W14 = reinterpret_cast<float4*>(W1);
        for (int i = tid; i < 64 * 8; i += 256) W14[i] = w14[i];
        if (tid < 32) W2s[tid] = fW2[tid];
        if (tid == 32) W2s[32] = fb2[0];
    }
    const long row0 = (long)blockIdx.x * BR;
    {
        const uint4* H4 = reinterpret_cast<const uint4*>(h2 + row0 * 64);
        if (tid < BR * 8) {
            int r = tid >> 3, q = tid & 7;
            bf8_to_f32(&Hin[r * LDH + q * 8], H4[tid]);
        }
    }
    __syncthreads();

    {
        const int rp = tid >> 4;
        const int cq = tid & 15;
        const int r0 = rp * 2, r1 = r0 + 1;
        const float4 bias = reinterpret_cast<const float4*>(fb0)[cq];
        float4 acc0 = bias, acc1 = bias;
#pragma unroll 2
        for (int k4 = 0; k4 < 64; k4 += 4) {
            const float4 a0 = *reinterpret_cast<const float4*>(&Hin[r0 * LDH + k4]);
            const float4 a1 = *reinterpret_cast<const float4*>(&Hin[r1 * LDH + k4]);
            const float4 w0 = *reinterpret_cast<const float4*>(&W0[(k4 + 0) * 64 + cq * 4]);
            const float4 w1 = *reinterpret_cast<const float4*>(&W0[(k4 + 1) * 64 + cq * 4]);
            const float4 w2 = *reinterpret_cast<const float4*>(&W0[(k4 + 2) * 64 + cq * 4]);
            const float4 w3 = *reinterpret_cast<const float4*>(&W0[(k4 + 3) * 64 + cq * 4]);
            fma4(acc0, a0, w0, w1, w2, w3);
            fma4(acc1, a1, w0, w1, w2, w3);
        }
        float4 t0, t1;
        t0.x = fast_tanh(acc0.x); t0.y = fast_tanh(acc0.y);
        t0.z = fast_tanh(acc0.z); t0.w = fast_tanh(acc0.w);
        t1.x = fast_tanh(acc1.x); t1.y = fast_tanh(acc1.y);
        t1.z = fast_tanh(acc1.z); t1.w = fast_tanh(acc1.w);
        *reinterpret_cast<float4*>(&Ht[r0 * LDH + cq * 4]) = t0;
        *reinterpret_cast<float4*>(&Ht[r1 * LDH + cq * 4]) = t1;
    }
    __syncthreads();

    {
        const int r = tid >> 3;
        const int cq = tid & 7;
        const float4 bias = reinterpret_cast<const float4*>(fb1)[cq];
        float4 acc0 = bias;
#pragma unroll 2
        for (int k4 = 0; k4 < 64; k4 += 4) {
            const float4 a0 = *reinterpret_cast<const float4*>(&Ht[r * LDH + k4]);
            const float4 w0 = *reinterpret_cast<const float4*>(&W1[(k4 + 0) * 32 + cq * 4]);
            const float4 w1 = *reinterpret_cast<const float4*>(&W1[(k4 + 1) * 32 + cq * 4]);
            const float4 w2 = *reinterpret_cast<const float4*>(&W1[(k4 + 2) * 32 + cq * 4]);
            const float4 w3 = *reinterpret_cast<const float4*>(&W1[(k4 + 3) * 32 + cq * 4]);
            fma4(acc0, a0, w0, w1, w2, w3);
        }
        Hs[r * 33 + cq * 4 + 0] = fast_tanh(acc0.x);
        Hs[r * 33 + cq * 4 + 1] = fast_tanh(acc0.y);
        Hs[r * 33 + cq * 4 + 2] = fast_tanh(acc0.z);
        Hs[r * 33 + cq * 4 + 3] = fast_tanh(acc0.w);
    }
    __syncthreads();

    if (tid < BR) {
        float a = W2s[32];
        for (int k = 0; k < 32; ++k) a = fmaf(Hs[tid * 33 + k], W2s[k], a);
        out[row0 + tid] = a;
    }
}

// ---------------- launch ----------------

extern "C" void kernel_launch(void* const* d_in, const int* in_sizes, int n_in,
                              void* d_out, int out_size, void* d_ws, size_t ws_size,
                              hipStream_t stream) {
    const float* x    = (const float*)d_in[0];
    const int*   eidx = (const int*)d_in[1];
    const float* cW0  = (const float*)d_in[2];
    const float* cb0  = (const float*)d_in[3];
    const float* cW1  = (const float*)d_in[4];
    const float* cb1  = (const float*)d_in[5];
    const float* fW0  = (const float*)d_in[6];
    const float* fb0  = (const float*)d_in[7];
    const float* fW1  = (const float*)d_in[8];
    const float* fb1  = (const float*)d_in[9];
    const float* fW2  = (const float*)d_in[10];
    const float* fb2  = (const float*)d_in[11];
    float* out = (float*)d_out;

    const int* src = eidx;
    const int* dst = eidx + N_EDGES;

    char* ws = (char*)d_ws;
    unsigned* rowptr  = (unsigned*)(ws);                  // 400,004 B
    float*    dinv    = (float*)   (ws + 400016);         // 400,000 B
    unsigned* cnt     = (unsigned*)(ws + 800016);         // 611,524 B
    unsigned* btot    = (unsigned*)(ws + 1411552);        // 1,564 B
    unsigned* bktbase = (unsigned*)(ws + 1413120);        // 1,568 B
    int*      ssrc    = (int*)     (ws + 1414688);        // 6,400,000 B
    ushort_t* xlb     = (ushort_t*)(ws + 7814688);        // 12,800,000 B
    unsigned* binned  = (unsigned*)(ws + 20614688);       // 6,400,000 B
    ushort_t* hb      = (ushort_t*)(ws + 27014688);       // 12,800,000 B -> ends 39,814,688

    const int gRow = N_NODES / 32;              // 3125 (k_fc)
    const int gGemm = (N_NODES + 63) / 64;      // 1563
    const int gAgg = N_NODES / 4;               // 25000

    // fused: conv0 GEMM (unscaled) + coarse count
    k_gemm0_count<<<GEMM0_BLOCKS + NBLK_A, 256, 0, stream>>>(x, cW0, xlb, dst, cnt);
    // CSR build
    k_bucket_scan<<<NB, 512, 0, stream>>>(cnt, btot);
    k_scan_bkt<<<1, 512, 0, stream>>>(btot, bktbase);
    k_bin<<<NBLK_A, 256, 0, stream>>>(src, dst, cnt, bktbase, binned);
    k_csr_fill2<<<NB, 256, 0, stream>>>(binned, bktbase, rowptr, dinv, ssrc);

    // conv0 aggregation (per-edge dinv[s] scaling)
    k_agg<false><<<gAgg, 256, 0, stream>>>(xlb, dinv, rowptr, ssrc, cb0, hb);
    // conv1: hb (bf16) -> xlb (bf16, pre-scaled by dinv)
    k_gemm_bfin<<<gGemm, 256, 0, stream>>>(hb, cW1, dinv, xlb);
    k_agg<true><<<gAgg, 256, 0, stream>>>(xlb, dinv, rowptr, ssrc, cb1, hb);
    // fc stack
    k_fc<<<gRow, 256, 0, stream>>>(hb, fW0, fb0, fW1, fb1, fW2, fb2, out);
}

// Round 13
// 219.525 us; speedup vs baseline: 7.0107x; 1.0523x over previous
//
#include <hip/hip_runtime.h>
#include <math.h>

#define N_NODES 100000
#define N_EDGES 1600000
#define NB     391   // buckets of 256 nodes
#define CHUNK  4096  // edges per chunk block
#define NBLK_A 391   // ceil(E/CHUNK)
#define GEMM0_BLOCKS 1563   // ceil(N/64)
#define EPT    16    // edges per thread in k_bin (CHUNK/256)

typedef unsigned short ushort_t;

__device__ inline unsigned short f2bf(float f) {
    unsigned u = __float_as_uint(f);
    unsigned r = (u + 0x7FFFu + ((u >> 16) & 1u)) >> 16;
    return (unsigned short)r;
}
// accumulate 2 packed bf16 into 2 fp32 (unit scale)
__device__ inline void acc2(float& a0, float& a1, unsigned u) {
    a0 += __uint_as_float(u << 16);
    a1 += __uint_as_float(u & 0xFFFF0000u);
}
// accumulate 2 packed bf16 scaled by s
__device__ inline void acc2s(float& a0, float& a1, unsigned u, float s) {
    a0 = fmaf(__uint_as_float(u << 16), s, a0);
    a1 = fmaf(__uint_as_float(u & 0xFFFF0000u), s, a1);
}
// tanh(x) = 1 - 2/(exp(2x)+1)
__device__ inline float fast_tanh(float x) {
    float e = __expf(2.0f * x);
    return fmaf(-2.0f, __builtin_amdgcn_rcpf(e + 1.0f), 1.0f);
}
__device__ inline void fma4(float4& acc, const float4 a,
                            const float4 w0, const float4 w1,
                            const float4 w2, const float4 w3) {
    acc.x = fmaf(a.x, w0.x, fmaf(a.y, w1.x, fmaf(a.z, w2.x, fmaf(a.w, w3.x, acc.x))));
    acc.y = fmaf(a.x, w0.y, fmaf(a.y, w1.y, fmaf(a.z, w2.y, fmaf(a.w, w3.y, acc.y))));
    acc.z = fmaf(a.x, w0.z, fmaf(a.y, w1.z, fmaf(a.z, w2.z, fmaf(a.w, w3.z, acc.z))));
    acc.w = fmaf(a.x, w0.w, fmaf(a.y, w1.w, fmaf(a.z, w2.w, fmaf(a.w, w3.w, acc.w))));
}
__device__ inline void bf8_to_f32(float* p, uint4 v) {
    p[0] = __uint_as_float(v.x << 16); p[1] = __uint_as_float(v.x & 0xFFFF0000u);
    p[2] = __uint_as_float(v.y << 16); p[3] = __uint_as_float(v.y & 0xFFFF0000u);
    p[4] = __uint_as_float(v.z << 16); p[5] = __uint_as_float(v.z & 0xFFFF0000u);
    p[6] = __uint_as_float(v.w << 16); p[7] = __uint_as_float(v.w & 0xFFFF0000u);
}

// ---------------- fused conv0 GEMM (unscaled) + coarse count ----------------
__global__ __launch_bounds__(256) void k_gemm0_count(const float* __restrict__ A,
                                                     const float* __restrict__ W,
                                                     ushort_t* __restrict__ C,
                                                     const int* __restrict__ dst,
                                                     unsigned* __restrict__ cnt) {
    constexpr int K = 128, OUT = 64, BR = 64, LDA = K + 4;
    __shared__ __align__(16) char smem[(K * OUT + BR * LDA) * 4];
    const int tid = threadIdx.x;

    if (blockIdx.x >= GEMM0_BLOCKS) {
        unsigned* h = (unsigned*)smem;
        const int cb = blockIdx.x - GEMM0_BLOCKS;
        const long e0 = (long)cb * CHUNK;
        for (int i = tid; i < NB; i += 256) h[i] = 0u;
        __syncthreads();
        for (int i = tid; i < CHUNK; i += 256) {
            long e = e0 + i;
            if (e < N_EDGES) atomicAdd(&h[((unsigned)dst[e]) >> 8], 1u);
        }
        __syncthreads();
        for (int b = tid; b < NB; b += 256) cnt[b * NBLK_A + cb] = h[b];
        return;
    }

    float* Wld = (float*)smem;
    float* Ald = Wld + K * OUT;
    const int row0 = blockIdx.x * BR;
    const int nrows = (N_NODES - row0 < BR) ? (N_NODES - row0) : BR;
    {
        const float4* W4 = reinterpret_cast<const float4*>(W);
        float4* Wl4 = reinterpret_cast<float4*>(Wld);
        for (int i = tid; i < K * OUT / 4; i += 256) Wl4[i] = W4[i];
        const float4* A4 = reinterpret_cast<const float4*>(A + (size_t)row0 * K);
        const int nv = nrows * (K / 4);
        for (int i = tid; i < nv; i += 256) {
            int r = i / (K / 4), q = i % (K / 4);
            *reinterpret_cast<float4*>(&Ald[r * LDA + q * 4]) = A4[i];
        }
    }
    __syncthreads();

    const int tr = tid >> 4, tc = tid & 15;
    const int r0 = tr * 4;
    float4 acc0 = {0,0,0,0}, acc1 = {0,0,0,0}, acc2v = {0,0,0,0}, acc3 = {0,0,0,0};
#pragma unroll 2
    for (int k4 = 0; k4 < K; k4 += 4) {
        const float4 a0 = *reinterpret_cast<const float4*>(&Ald[(r0 + 0) * LDA + k4]);
        const float4 a1 = *reinterpret_cast<const float4*>(&Ald[(r0 + 1) * LDA + k4]);
        const float4 a2 = *reinterpret_cast<const float4*>(&Ald[(r0 + 2) * LDA + k4]);
        const float4 a3 = *reinterpret_cast<const float4*>(&Ald[(r0 + 3) * LDA + k4]);
        const float4 w0 = *reinterpret_cast<const float4*>(&Wld[(k4 + 0) * OUT + tc * 4]);
        const float4 w1 = *reinterpret_cast<const float4*>(&Wld[(k4 + 1) * OUT + tc * 4]);
        const float4 w2 = *reinterpret_cast<const float4*>(&Wld[(k4 + 2) * OUT + tc * 4]);
        const float4 w3 = *reinterpret_cast<const float4*>(&Wld[(k4 + 3) * OUT + tc * 4]);
        fma4(acc0, a0, w0, w1, w2, w3);
        fma4(acc1, a1, w0, w1, w2, w3);
        fma4(acc2v, a2, w0, w1, w2, w3);
        fma4(acc3, a3, w0, w1, w2, w3);
    }
    float4 accs[4] = {acc0, acc1, acc2v, acc3};
#pragma unroll
    for (int i = 0; i < 4; ++i) {
        const int r = r0 + i;
        if (r < nrows) {
            ushort4 o;
            o.x = f2bf(accs[i].x); o.y = f2bf(accs[i].y);
            o.z = f2bf(accs[i].z); o.w = f2bf(accs[i].w);
            *reinterpret_cast<ushort4*>(&C[(size_t)(row0 + r) * 64 + tc * 4]) = o;
        }
    }
}

// ---------------- CSR build (rest) ----------------

__global__ __launch_bounds__(512) void k_bucket_scan(unsigned* __restrict__ cnt,
                                                     unsigned* __restrict__ btot) {
    __shared__ unsigned s[512];
    const int tid = threadIdx.x;
    const int b = blockIdx.x;
    unsigned v = (tid < NBLK_A) ? cnt[b * NBLK_A + tid] : 0u;
    s[tid] = v;
    __syncthreads();
    for (int o = 1; o < 512; o <<= 1) {
        unsigned t = (tid >= o) ? s[tid - o] : 0u;
        __syncthreads();
        s[tid] += t;
        __syncthreads();
    }
    if (tid < NBLK_A) cnt[b * NBLK_A + tid] = s[tid] - v;
    if (tid == NBLK_A - 1) btot[b] = s[tid];
}

__global__ __launch_bounds__(512) void k_scan_bkt(const unsigned* __restrict__ btot,
                                                  unsigned* __restrict__ bktbase) {
    __shared__ unsigned s[512];
    const int tid = threadIdx.x;
    unsigned v = (tid < NB) ? btot[tid] : 0u;
    s[tid] = v;
    __syncthreads();
    for (int o = 1; o < 512; o <<= 1) {
        unsigned t = (tid >= o) ? s[tid - o] : 0u;
        __syncthreads();
        s[tid] += t;
        __syncthreads();
    }
    if (tid < NB) bktbase[tid] = s[tid] - v;
    if (tid == NB - 1) bktbase[NB] = s[tid];   // == E
}

// phase A: LDS multisplit; edges register-cached across both passes
__global__ __launch_bounds__(256) void k_bin(const int* __restrict__ src,
                                             const int* __restrict__ dst,
                                             const unsigned* __restrict__ cnt,
                                             const unsigned* __restrict__ bktbase,
                                             unsigned* __restrict__ binned) {
    __shared__ unsigned cntA[NB];
    __shared__ unsigned excl[NB];
    __shared__ unsigned gbase[NB];
    __shared__ unsigned scanbuf[512];
    __shared__ unsigned data[CHUNK];
    __shared__ ushort_t bkt16[CHUNK];
    const int tid = threadIdx.x;
    const long e0 = (long)blockIdx.x * CHUNK;
    const int n = (N_EDGES - e0 < CHUNK) ? (int)(N_EDGES - e0) : CHUNK;

    unsigned dc[EPT];
    unsigned sc[EPT];
#pragma unroll
    for (int u = 0; u < EPT; ++u) {
        const int i = u * 256 + tid;
        if (i < n) {
            dc[u] = (unsigned)dst[e0 + i];
            sc[u] = (unsigned)src[e0 + i];
        } else {
            dc[u] = 0xFFFFFFFFu;
        }
    }
    for (int i = tid; i < NB; i += 256) cntA[i] = 0u;
    __syncthreads();
#pragma unroll
    for (int u = 0; u < EPT; ++u)
        if (dc[u] != 0xFFFFFFFFu) atomicAdd(&cntA[dc[u] >> 8], 1u);
    __syncthreads();
    scanbuf[tid] = (tid < NB) ? cntA[tid] : 0u;
    scanbuf[tid + 256] = (tid + 256 < NB) ? cntA[tid + 256] : 0u;
    __syncthreads();
    for (int o = 1; o < 512; o <<= 1) {
        unsigned v0 = (tid >= o) ? scanbuf[tid - o] : 0u;
        unsigned v1 = (tid + 256 >= o) ? scanbuf[tid + 256 - o] : 0u;
        __syncthreads();
        scanbuf[tid] += v0;
        scanbuf[tid + 256] += v1;
        __syncthreads();
    }
    for (int b = tid; b < NB; b += 256) {
        excl[b] = scanbuf[b] - cntA[b];
        gbase[b] = bktbase[b] + cnt[b * NBLK_A + blockIdx.x];
    }
    __syncthreads();
    for (int i = tid; i < NB; i += 256) cntA[i] = 0u;
    __syncthreads();
#pragma unroll
    for (int u = 0; u < EPT; ++u) {
        if (dc[u] != 0xFFFFFFFFu) {
            unsigned d = dc[u];
            unsigned b = d >> 8;
            unsigned slot = excl[b] + atomicAdd(&cntA[b], 1u);
            data[slot] = (sc[u] << 8) | (d & 255u);
            bkt16[slot] = (ushort_t)b;
        }
    }
    __syncthreads();
    for (int i = tid; i < n; i += 256) {
        unsigned b = bkt16[i];
        binned[gbase[b] + (unsigned)i - excl[b]] = data[i];
    }
}

// phase B: per-bucket CSR fill; derives degree/rowptr/dinv from binned
__global__ __launch_bounds__(256) void k_csr_fill2(const unsigned* __restrict__ binned,
                                                   const unsigned* __restrict__ bktbase,
                                                   unsigned* __restrict__ rowptr,
                                                   float* __restrict__ dinv,
                                                   int* __restrict__ ssrc) {
    __shared__ unsigned cnt[256];
    __shared__ unsigned s[256];
    __shared__ unsigned cur[256];
    const int b = blockIdx.x;
    const int tid = threadIdx.x;
    const int n0 = b * 256;
    const unsigned beg = bktbase[b], end = bktbase[b + 1];
    cnt[tid] = 0u;
    __syncthreads();
    for (unsigned i = beg + tid; i < end; i += 256)
        atomicAdd(&cnt[binned[i] & 255u], 1u);
    __syncthreads();
    const unsigned v = cnt[tid];
    s[tid] = v;
    __syncthreads();
    for (int o = 1; o < 256; o <<= 1) {
        unsigned t = (tid >= o) ? s[tid - o] : 0u;
        __syncthreads();
        s[tid] += t;
        __syncthreads();
    }
    const unsigned excl = s[tid] - v;
    const int node = n0 + tid;
    if (node < N_NODES) {
        rowptr[node] = beg + excl;
        dinv[node] = rsqrtf((float)(v + 1u));
        if (node == N_NODES - 1) rowptr[N_NODES] = end;   // == E
    }
    cur[tid] = beg + excl;
    __syncthreads();
    for (unsigned i = beg + tid; i < end; i += 256) {
        unsigned p = binned[i];
        unsigned pos = atomicAdd(&cur[p & 255u], 1u);
        ssrc[pos] = (int)(p >> 8);
    }
}

// ---------------- dense layers ----------------

// conv1 GEMM: A bf16 in, output scaled by dinv[row]; K=64
__global__ __launch_bounds__(256) void k_gemm_bfin(const ushort_t* __restrict__ A,
                                                   const float* __restrict__ W,
                                                   const float* __restrict__ dinv,
                                                   ushort_t* __restrict__ C) {
    constexpr int K = 64, OUT = 64, BR = 64, LDA = K + 4;
    __shared__ float Wld[K * OUT];
    __shared__ float Ald[BR * LDA];
    const int tid = threadIdx.x;
    const int row0 = blockIdx.x * BR;
    const int nrows = (N_NODES - row0 < BR) ? (N_NODES - row0) : BR;

    {
        const float4* W4 = reinterpret_cast<const float4*>(W);
        float4* Wl4 = reinterpret_cast<float4*>(Wld);
        for (int i = tid; i < K * OUT / 4; i += 256) Wl4[i] = W4[i];
        const uint4* A4 = reinterpret_cast<const uint4*>(A + (size_t)row0 * K);
        const int nv = nrows * 8;
        for (int i = tid; i < nv; i += 256) {
            int r = i >> 3, q = i & 7;
            bf8_to_f32(&Ald[r * LDA + q * 8], A4[i]);
        }
    }
    __syncthreads();

    const int tr = tid >> 4, tc = tid & 15;
    const int r0 = tr * 4;
    float4 acc0 = {0,0,0,0}, acc1 = {0,0,0,0}, acc2v = {0,0,0,0}, acc3 = {0,0,0,0};
#pragma unroll 2
    for (int k4 = 0; k4 < K; k4 += 4) {
        const float4 a0 = *reinterpret_cast<const float4*>(&Ald[(r0 + 0) * LDA + k4]);
        const float4 a1 = *reinterpret_cast<const float4*>(&Ald[(r0 + 1) * LDA + k4]);
        const float4 a2 = *reinterpret_cast<const float4*>(&Ald[(r0 + 2) * LDA + k4]);
        const float4 a3 = *reinterpret_cast<const float4*>(&Ald[(r0 + 3) * LDA + k4]);
        const float4 w0 = *reinterpret_cast<const float4*>(&Wld[(k4 + 0) * OUT + tc * 4]);
        const float4 w1 = *reinterpret_cast<const float4*>(&Wld[(k4 + 1) * OUT + tc * 4]);
        const float4 w2 = *reinterpret_cast<const float4*>(&Wld[(k4 + 2) * OUT + tc * 4]);
        const float4 w3 = *reinterpret_cast<const float4*>(&Wld[(k4 + 3) * OUT + tc * 4]);
        fma4(acc0, a0, w0, w1, w2, w3);
        fma4(acc1, a1, w0, w1, w2, w3);
        fma4(acc2v, a2, w0, w1, w2, w3);
        fma4(acc3, a3, w0, w1, w2, w3);
    }
    float4 accs[4] = {acc0, acc1, acc2v, acc3};
#pragma unroll
    for (int i = 0; i < 4; ++i) {
        const int r = r0 + i;
        if (r < nrows) {
            const float di = dinv[row0 + r];
            ushort4 o;
            o.x = f2bf(accs[i].x * di);
            o.y = f2bf(accs[i].y * di);
            o.z = f2bf(accs[i].z * di);
            o.w = f2bf(accs[i].w * di);
            *reinterpret_cast<ushort4*>(&C[(size_t)(row0 + r) * 64 + tc * 4]) = o;
        }
    }
}

// one node per 64-lane wave; 8 lane-groups x 8 lanes; lane loads uint4 = 8 bf16.
template<bool SCALED_IN>
__global__ __launch_bounds__(256) void k_agg(const ushort_t* __restrict__ xlb,
                                             const float* __restrict__ dinv,
                                             const unsigned* __restrict__ rowptr,
                                             const int* __restrict__ ssrc,
                                             const float* __restrict__ bias,
                                             ushort_t* __restrict__ hb) {
    const int node = blockIdx.x * 4 + (threadIdx.x >> 6);
    const int lane = threadIdx.x & 63;
    const int g = lane >> 3;
    const int l = lane & 7;
    const uint4* xb4 = reinterpret_cast<const uint4*>(xlb);

    const unsigned beg = rowptr[node], end = rowptr[node + 1];
    float a[8] = {0.f,0.f,0.f,0.f,0.f,0.f,0.f,0.f};
    float b[8] = {0.f,0.f,0.f,0.f,0.f,0.f,0.f,0.f};
    if (g == 0) {   // self-loop
        const uint4 v = xb4[(size_t)node * 8 + l];
        if (SCALED_IN) {
            acc2(a[0], a[1], v.x); acc2(a[2], a[3], v.y);
            acc2(a[4], a[5], v.z); acc2(a[6], a[7], v.w);
        } else {
            const float dn = dinv[node];
            acc2s(a[0], a[1], v.x, dn); acc2s(a[2], a[3], v.y, dn);
            acc2s(a[4], a[5], v.z, dn); acc2s(a[6], a[7], v.w, dn);
        }
    }
    unsigned j = beg + g;
    for (; j + 8 < end; j += 16) {
        const int s0 = ssrc[j];
        const int s1 = ssrc[j + 8];
        const uint4 v0 = xb4[(size_t)s0 * 8 + l];
        const uint4 v1 = xb4[(size_t)s1 * 8 + l];
        if (SCALED_IN) {
            acc2(a[0], a[1], v0.x); acc2(a[2], a[3], v0.y);
            acc2(a[4], a[5], v0.z); acc2(a[6], a[7], v0.w);
            acc2(b[0], b[1], v1.x); acc2(b[2], b[3], v1.y);
            acc2(b[4], b[5], v1.z); acc2(b[6], b[7], v1.w);
        } else {
            const float d0 = dinv[s0];
            const float d1 = dinv[s1];
            acc2s(a[0], a[1], v0.x, d0); acc2s(a[2], a[3], v0.y, d0);
            acc2s(a[4], a[5], v0.z, d0); acc2s(a[6], a[7], v0.w, d0);
            acc2s(b[0], b[1], v1.x, d1); acc2s(b[2], b[3], v1.y, d1);
            acc2s(b[4], b[5], v1.z, d1); acc2s(b[6], b[7], v1.w, d1);
        }
    }
    if (j < end) {
        const int s0 = ssrc[j];
        const uint4 v = xb4[(size_t)s0 * 8 + l];
        if (SCALED_IN) {
            acc2(a[0], a[1], v.x); acc2(a[2], a[3], v.y);
            acc2(a[4], a[5], v.z); acc2(a[6], a[7], v.w);
        } else {
            const float d0 = dinv[s0];
            acc2s(a[0], a[1], v.x, d0); acc2s(a[2], a[3], v.y, d0);
            acc2s(a[4], a[5], v.z, d0); acc2s(a[6], a[7], v.w, d0);
        }
    }
#pragma unroll
    for (int i = 0; i < 8; ++i) a[i] += b[i];
#pragma unroll
    for (int i = 0; i < 8; ++i) {
        a[i] += __shfl_xor(a[i], 8);
        a[i] += __shfl_xor(a[i], 16);
        a[i] += __shfl_xor(a[i], 32);
    }
    if (g == 0) {
        const float di = dinv[node];
        const float4 b0 = reinterpret_cast<const float4*>(bias)[l * 2];
        const float4 b1 = reinterpret_cast<const float4*>(bias)[l * 2 + 1];
        float r0 = fast_tanh(fmaf(a[0], di, b0.x));
        float r1 = fast_tanh(fmaf(a[1], di, b0.y));
        float r2 = fast_tanh(fmaf(a[2], di, b0.z));
        float r3 = fast_tanh(fmaf(a[3], di, b0.w));
        float r4 = fast_tanh(fmaf(a[4], di, b1.x));
        float r5 = fast_tanh(fmaf(a[5], di, b1.y));
        float r6 = fast_tanh(fmaf(a[6], di, b1.z));
        float r7 = fast_tanh(fmaf(a[7], di, b1.w));
        uint4 o;
        o.x = (unsigned)f2bf(r0) | ((unsigned)f2bf(r1) << 16);
        o.y = (unsigned)f2bf(r2) | ((unsigned)f2bf(r3) << 16);
        o.z = (unsigned)f2bf(r4) | ((unsigned)f2bf(r5) << 16);
        o.w = (unsigned)f2bf(r6) | ((unsigned)f2bf(r7) << 16);
        reinterpret_cast<uint4*>(hb)[(size_t)node * 8 + l] = o;
    }
}

// fused FC stack, BR=64, 4x4 register tiles, fp32; fc0 output staged through
// registers back into Hin (saves an LDS buffer -> 3 blocks/CU).
__global__ __launch_bounds__(256, 3) void k_fc(const ushort_t* __restrict__ h2,
                                               const float* __restrict__ fW0, const float* __restrict__ fb0,
                                               const float* __restrict__ fW1, const float* __restrict__ fb1,
                                               const float* __restrict__ fW2, const float* __restrict__ fb2,
                                               float* __restrict__ out) {
    constexpr int BR = 64;
    constexpr int LDH = 68;
    __shared__ float W0[64 * 64];    // 16 KB
    __shared__ float W1[64 * 32];    // 8 KB
    __shared__ float Hin[BR * LDH];  // 17.4 KB
    __shared__ float Hs[BR * 33];    // 8.45 KB
    __shared__ float W2s[33];
    const int tid = threadIdx.x;
    const int row0 = blockIdx.x * BR;
    {
        const float4* w04 = reinterpret_cast<const float4*>(fW0);
        float4* W04 = reinterpret_cast<float4*>(W0);
        for (int i = tid; i < 64 * 16; i += 256) W04[i] = w04[i];
        const float4* w14 = reinterpret_cast<const float4*>(fW1);
        float4* W14 = reinterpret_cast<float4*>(W1);
        for (int i = tid; i < 64 * 8; i += 256) W14[i] = w14[i];
        if (tid < 32) W2s[tid] = fW2[tid];
        if (tid == 32) W2s[32] = fb2[0];
    }
    {
        const uint4* H4 = reinterpret_cast<const uint4*>(h2 + (size_t)row0 * 64);
        for (int i = tid; i < BR * 8; i += 256) {
            int r = i >> 3, q = i & 7;
            bf8_to_f32(&Hin[r * LDH + q * 8], H4[i]);   // OOB rows read garbage; stores guarded
        }
    }
    __syncthreads();

    // ---- fc0: 64x64, tile 4 rows x 4 cols, 256 threads ----
    const int tr = tid >> 4, tc = tid & 15;
    const int r0 = tr * 4;
    float4 t0, t1, t2, t3;
    {
        const float4 bias = reinterpret_cast<const float4*>(fb0)[tc];
        float4 acc0 = bias, acc1 = bias, acc2v = bias, acc3 = bias;
#pragma unroll 2
        for (int k4 = 0; k4 < 64; k4 += 4) {
            const float4 a0 = *reinterpret_cast<const float4*>(&Hin[(r0 + 0) * LDH + k4]);
            const float4 a1 = *reinterpret_cast<const float4*>(&Hin[(r0 + 1) * LDH + k4]);
            const float4 a2 = *reinterpret_cast<const float4*>(&Hin[(r0 + 2) * LDH + k4]);
            const float4 a3 = *reinterpret_cast<const float4*>(&Hin[(r0 + 3) * LDH + k4]);
            const float4 w0 = *reinterpret_cast<const float4*>(&W0[(k4 + 0) * 64 + tc * 4]);
            const float4 w1 = *reinterpret_cast<const float4*>(&W0[(k4 + 1) * 64 + tc * 4]);
            const float4 w2 = *reinterpret_cast<const float4*>(&W0[(k4 + 2) * 64 + tc * 4]);
            const float4 w3 = *reinterpret_cast<const float4*>(&W0[(k4 + 3) * 64 + tc * 4]);
            fma4(acc0, a0, w0, w1, w2, w3);
            fma4(acc1, a1, w0, w1, w2, w3);
            fma4(acc2v, a2, w0, w1, w2, w3);
            fma4(acc3, a3, w0, w1, w2, w3);
        }
        t0.x = fast_tanh(acc0.x); t0.y = fast_tanh(acc0.y); t0.z = fast_tanh(acc0.z); t0.w = fast_tanh(acc0.w);
        t1.x = fast_tanh(acc1.x); t1.y = fast_tanh(acc1.y); t1.z = fast_tanh(acc1.z); t1.w = fast_tanh(acc1.w);
        t2.x = fast_tanh(acc2v.x); t2.y = fast_tanh(acc2v.y); t2.z = fast_tanh(acc2v.z); t2.w = fast_tanh(acc2v.w);
        t3.x = fast_tanh(acc3.x); t3.y = fast_tanh(acc3.y); t3.z = fast_tanh(acc3.z); t3.w = fast_tanh(acc3.w);
    }
    __syncthreads();   // all fc0 reads of Hin complete
    *reinterpret_cast<float4*>(&Hin[(r0 + 0) * LDH + tc * 4]) = t0;
    *reinterpret_cast<float4*>(&Hin[(r0 + 1) * LDH + tc * 4]) = t1;
    *reinterpret_cast<float4*>(&Hin[(r0 + 2) * LDH + tc * 4]) = t2;
    *reinterpret_cast<float4*>(&Hin[(r0 + 3) * LDH + tc * 4]) = t3;
    __syncthreads();

    // ---- fc1: 64x32, tile 2 rows x 4 cols, 256 threads ----
    {
        const int rp = tid >> 3;          // 0..31 -> rows 2rp, 2rp+1
        const int cq = tid & 7;           // cols 4cq..4cq+3
        const int rr0 = rp * 2, rr1 = rr0 + 1;
        const float4 bias = reinterpret_cast<const float4*>(fb1)[cq];
        float4 acc0 = bias, acc1 = bias;
#pragma unroll 2
        for (int k4 = 0; k4 < 64; k4 += 4) {
            const float4 a0 = *reinterpret_cast<const float4*>(&Hin[rr0 * LDH + k4]);
            const float4 a1 = *reinterpret_cast<const float4*>(&Hin[rr1 * LDH + k4]);
            const float4 w0 = *reinterpret_cast<const float4*>(&W1[(k4 + 0) * 32 + cq * 4]);
            const float4 w1 = *reinterpret_cast<const float4*>(&W1[(k4 + 1) * 32 + cq * 4]);
            const float4 w2 = *reinterpret_cast<const float4*>(&W1[(k4 + 2) * 32 + cq * 4]);
            const float4 w3 = *reinterpret_cast<const float4*>(&W1[(k4 + 3) * 32 + cq * 4]);
            fma4(acc0, a0, w0, w1, w2, w3);
            fma4(acc1, a1, w0, w1, w2, w3);
        }
        Hs[rr0 * 33 + cq * 4 + 0] = fast_tanh(acc0.x);
        Hs[rr0 * 33 + cq * 4 + 1] = fast_tanh(acc0.y);
        Hs[rr0 * 33 + cq * 4 + 2] = fast_tanh(acc0.z);
        Hs[rr0 * 33 + cq * 4 + 3] = fast_tanh(acc0.w);
        Hs[rr1 * 33 + cq * 4 + 0] = fast_tanh(acc1.x);
        Hs[rr1 * 33 + cq * 4 + 1] = fast_tanh(acc1.y);
        Hs[rr1 * 33 + cq * 4 + 2] = fast_tanh(acc1.z);
        Hs[rr1 * 33 + cq * 4 + 3] = fast_tanh(acc1.w);
    }
    __syncthreads();

    // ---- fc2: 32 -> 1, 64 rows ----
    if (tid < BR && row0 + tid < N_NODES) {
        float a = W2s[32];
        for (int k = 0; k < 32; ++k) a = fmaf(Hs[tid * 33 + k], W2s[k], a);
        out[row0 + tid] = a;
    }
}

// ---------------- launch ----------------

extern "C" void kernel_launch(void* const* d_in, const int* in_sizes, int n_in,
                              void* d_out, int out_size, void* d_ws, size_t ws_size,
                              hipStream_t stream) {
    const float* x    = (const float*)d_in[0];
    const int*   eidx = (const int*)d_in[1];
    const float* cW0  = (const float*)d_in[2];
    const float* cb0  = (const float*)d_in[3];
    const float* cW1  = (const float*)d_in[4];
    const float* cb1  = (const float*)d_in[5];
    const float* fW0  = (const float*)d_in[6];
    const float* fb0  = (const float*)d_in[7];
    const float* fW1  = (const float*)d_in[8];
    const float* fb1  = (const float*)d_in[9];
    const float* fW2  = (const float*)d_in[10];
    const float* fb2  = (const float*)d_in[11];
    float* out = (float*)d_out;

    const int* src = eidx;
    const int* dst = eidx + N_EDGES;

    char* ws = (char*)d_ws;
    unsigned* rowptr  = (unsigned*)(ws);                  // 400,004 B
    float*    dinv    = (float*)   (ws + 400016);         // 400,000 B
    unsigned* cnt     = (unsigned*)(ws + 800016);         // 611,524 B
    unsigned* btot    = (unsigned*)(ws + 1411552);        // 1,564 B
    unsigned* bktbase = (unsigned*)(ws + 1413120);        // 1,568 B
    int*      ssrc    = (int*)     (ws + 1414688);        // 6,400,000 B
    ushort_t* xlb     = (ushort_t*)(ws + 7814688);        // 12,800,000 B
    unsigned* binned  = (unsigned*)(ws + 20614688);       // 6,400,000 B
    ushort_t* hb      = (ushort_t*)(ws + 27014688);       // 12,800,000 B -> ends 39,814,688

    const int gGemm = (N_NODES + 63) / 64;      // 1563
    const int gAgg = N_NODES / 4;               // 25000

    // fused: conv0 GEMM (unscaled) + coarse count
    k_gemm0_count<<<GEMM0_BLOCKS + NBLK_A, 256, 0, stream>>>(x, cW0, xlb, dst, cnt);
    // CSR build
    k_bucket_scan<<<NB, 512, 0, stream>>>(cnt, btot);
    k_scan_bkt<<<1, 512, 0, stream>>>(btot, bktbase);
    k_bin<<<NBLK_A, 256, 0, stream>>>(src, dst, cnt, bktbase, binned);
    k_csr_fill2<<<NB, 256, 0, stream>>>(binned, bktbase, rowptr, dinv, ssrc);

    // conv0 aggregation (per-edge dinv[s] scaling)
    k_agg<false><<<gAgg, 256, 0, stream>>>(xlb, dinv, rowptr, ssrc, cb0, hb);
    // conv1: hb (bf16) -> xlb (bf16, pre-scaled by dinv)
    k_gemm_bfin<<<gGemm, 256, 0, stream>>>(hb, cW1, dinv, xlb);
    k_agg<true><<<gAgg, 256, 0, stream>>>(xlb, dinv, rowptr, ssrc, cb1, hb);
    // fc stack (BR=64)
    k_fc<<<gGemm, 256, 0, stream>>>(hb, fW0, fb0, fW1, fb1, fW2, fb2, out);
}